// Round 3
// baseline (518.882 us; speedup 1.0000x reference)
//
#include <hip/hip_runtime.h>
#include <hip/hip_bf16.h>

namespace {

constexpr int Bn = 2, Sn = 2048, Hn = 16, Dn = 128;
constexpr int QBLK = 128;   // 4 q-waves x 32 queries
constexpr int KVBLK = 32;   // keys per chunk; superstep = 4 chunks (one per key-group)
constexpr int RS = Hn * Dn; // 2048 floats
constexpr float QSCALE = 0.08838834764831845f * 1.4426950408889634f; // 1/sqrt(D)*log2(e)

typedef __bf16 bf16x8 __attribute__((ext_vector_type(8)));
typedef __bf16 bf16x2 __attribute__((ext_vector_type(2)));
typedef float  f32x16 __attribute__((ext_vector_type(16)));

__device__ __forceinline__ f32x16 mfma32(bf16x8 a, bf16x8 b, f32x16 c) {
  return __builtin_amdgcn_mfma_f32_32x32x16_bf16(a, b, c, 0, 0, 0);
}
__device__ __forceinline__ unsigned pack2(float a, float b) {
  union { __bf16 h[2]; unsigned u; } r;
  r.h[0] = (__bf16)a; r.h[1] = (__bf16)b;
  return r.u;
}
__device__ __forceinline__ float pair_max(float x) { return fmaxf(x, __shfl_xor(x, 32)); }
__device__ __forceinline__ float pair_sum(float x) { return x + __shfl_xor(x, 32); }
__device__ __forceinline__ float f4e(const float4& v, int j) {
  return j == 0 ? v.x : j == 1 ? v.y : j == 2 ? v.z : v.w;
}
__device__ __forceinline__ float lane_bcast(int row, float v) {
  return __uint_as_float(__builtin_amdgcn_ds_bpermute(row * 4, __float_as_uint(v)));
}

// lgkm-only barrier: publish LDS, leave register-destined global prefetches in flight.
__device__ __forceinline__ void pipeline_barrier() {
  __builtin_amdgcn_sched_barrier(0);
  asm volatile("s_waitcnt lgkmcnt(0)" ::: "memory");
  __builtin_amdgcn_s_barrier();
  __builtin_amdgcn_sched_barrier(0);
}

// Balanced schedule: 256 blocks (1/CU), 16 waves each (4 key-groups x 4 q-waves).
// Block p processes tiles (15-p) then (p) sequentially: (16-p)+(p+1) = 17
// supersteps for EVERY block -> no solo phase, constant 16-wave occupancy.
// NOTE: __launch_bounds__(1024) WITHOUT a min-waves arg — R2's (1024,4) made
// the allocator target 64 VGPRs -> 700 MB of scratch spill (WRITE_SIZE 23x).
// The 16-wave workgroup already implies 4 waves/SIMD; cap is 128 like R1.
__global__ __launch_bounds__(1024)
void fa_fwd(const float* __restrict__ Q, const float* __restrict__ K,
            const float* __restrict__ V, float* __restrict__ O)
{
  __shared__ __align__(16) __bf16 Klds[2][4][KVBLK * 128]; // 64 KB, dbuf by superstep
  __shared__ __align__(16) __bf16 Vt[2][4][128 * KVBLK];   // 64 KB, dbuf by superstep

  const int tid  = threadIdx.x;
  const int lane = tid & 63;
  const int wave = tid >> 6;    // 0..15
  const int col  = lane & 31;
  const int hi   = lane >> 5;
  const int grp  = wave >> 2;   // key-group 0..3: chunk 4t+grp
  const int wq   = wave & 3;    // q-wave within group: rows q0w..q0w+31

  // 4 heads per XCD (same-L2 K/V); 8 tile-pairs per head.
  const int xcd  = (int)blockIdx.x & 7;
  const int s    = (int)blockIdx.x >> 3;    // 0..31
  const int hidx = xcd * 4 + (s & 3);       // 0..31
  const int b    = hidx >> 4, h = hidx & 15;
  const int p    = s >> 2;                  // tile-pair 0..7
  const size_t base = ((size_t)b * Sn) * RS + (size_t)h * Dn;

  // staging: quarter sq (== grp for compute waves) stages chunk 4*ss+sq
  const int sq = tid >> 8, ht = tid & 255;
  const int skey = ht >> 3, sd = (ht & 7) * 16;
  const int vkey = (ht & 15) * 2, vd = (ht >> 4) * 8;

  float4 kr[4], vr[4];
  auto loadK = [&](int ss) {
    const int kv0 = (4 * ss + sq) * KVBLK;
    const float* kp = K + base + (size_t)(kv0 + skey) * RS + sd;
#pragma unroll
    for (int i = 0; i < 4; ++i) kr[i] = *(const float4*)(kp + 4 * i);
  };
  auto loadV = [&](int ss) {
    const int kv0 = (4 * ss + sq) * KVBLK;
    const float* vp = V + base + (size_t)(kv0 + vkey) * RS + vd;
    vr[0] = *(const float4*)(vp);
    vr[1] = *(const float4*)(vp + 4);
    vr[2] = *(const float4*)(vp + RS);
    vr[3] = *(const float4*)(vp + RS + 4);
  };
  auto stageK = [&](int ss) {
    char* kb = (char*)&Klds[ss & 1][sq][0];
    const int kbase = skey * 256 + sd * 2;
    const int kswz  = (skey & 7) << 4;
#pragma unroll
    for (int i = 0; i < 2; ++i) {
      bf16x8 f;
      f[0] = (__bf16)kr[2*i].x;   f[1] = (__bf16)kr[2*i].y;
      f[2] = (__bf16)kr[2*i].z;   f[3] = (__bf16)kr[2*i].w;
      f[4] = (__bf16)kr[2*i+1].x; f[5] = (__bf16)kr[2*i+1].y;
      f[6] = (__bf16)kr[2*i+1].z; f[7] = (__bf16)kr[2*i+1].w;
      *(bf16x8*)(kb + ((kbase + 16 * i) ^ kswz)) = f;
    }
  };
  auto stageV = [&](int ss) {
    char* vb = (char*)&Vt[ss & 1][sq][0];
#pragma unroll
    for (int j = 0; j < 8; ++j) {
      const int d = vd + j;
      bf16x2 w;
      w[0] = (__bf16)f4e(vr[j >> 2], j & 3);
      w[1] = (__bf16)f4e(vr[2 + (j >> 2)], j & 3);
      const int addr = (d * 64 + vkey * 2) ^ ((d & 3) << 4) ^ (((d >> 3) & 1) << 6);
      *(bf16x2*)(vb + addr) = w;
    }
  };

  const int cswz = (col & 7) << 4;
  const int vswz = ((col & 3) << 4) ^ (((col >> 3) & 1) << 6);

#pragma unroll 1
  for (int tp = 0; tp < 2; ++tp) {
    const int qt  = tp ? p : (15 - p);
    const int q0w = qt * QBLK + wq * 32;
    const int T   = qt + 1;              // supersteps of 128 keys

    // ---- Q fragments, scaled ----
    bf16x8 qf[8];
    {
      const float* qp = Q + base + (size_t)(q0w + col) * RS + hi * 8;
#pragma unroll
      for (int kk = 0; kk < 8; ++kk) {
        float4 a = *(const float4*)(qp + kk * 16);
        float4 c2 = *(const float4*)(qp + kk * 16 + 4);
        bf16x8 f;
        f[0] = (__bf16)(a.x * QSCALE);  f[1] = (__bf16)(a.y * QSCALE);
        f[2] = (__bf16)(a.z * QSCALE);  f[3] = (__bf16)(a.w * QSCALE);
        f[4] = (__bf16)(c2.x * QSCALE); f[5] = (__bf16)(c2.y * QSCALE);
        f[6] = (__bf16)(c2.z * QSCALE); f[7] = (__bf16)(c2.w * QSCALE);
        qf[kk] = f;
      }
    }

    f32x16 o0 = {}, o1 = {}, o2 = {}, o3 = {};
    float m = -1e30f, l = 0.f;

    // ---- prologue ----
    loadK(0); loadV(0);
    stageK(0);
    if (1 < T) loadK(1);
    stageV(0);
    if (1 < T) loadV(1);
    if (1 < T) stageK(1);
    if (2 < T) loadK(2);
    pipeline_barrier();              // K0,(K1),V0 published

    // S(0)
    f32x16 st_cur = {};
    if (grp * KVBLK <= q0w + 31) {
      const char* kb = (const char*)&Klds[0][grp][0];
      __builtin_amdgcn_s_setprio(1);
#pragma unroll
      for (int kk = 0; kk < 8; ++kk) {
        bf16x8 ka = *(const bf16x8*)(kb + ((col * 256 + kk * 32 + hi * 16) ^ cswz));
        st_cur = mfma32(ka, qf[kk], st_cur);
      }
      __builtin_amdgcn_s_setprio(0);
    }
    pipeline_barrier();              // fence Klds[0] reads vs iter-0 stageK(2)

#pragma unroll 1
    for (int t = 0; t < T; ++t) {
      // ---- QK^T(t+1) on MFMA pipe; softmax(t)+PV(t) overlap on VALU ----
      f32x16 stn = {};
      const int icn = 4 * (t + 1) + grp;
      if (t + 1 < T && icn * KVBLK <= q0w + 31) {
        const char* kb = (const char*)&Klds[(t + 1) & 1][grp][0];
        __builtin_amdgcn_s_setprio(1);
#pragma unroll
        for (int kk = 0; kk < 8; ++kk) {
          bf16x8 ka = *(const bf16x8*)(kb + ((col * 256 + kk * 32 + hi * 16) ^ cswz));
          stn = mfma32(ka, qf[kk], stn);
        }
        __builtin_amdgcn_s_setprio(0);
      }

      // ---- stage next buffers (consume last iter's loads), issue new loads ----
      if (t + 2 < T) stageK(t + 2);
      if (t + 1 < T) stageV(t + 1);
      if (t + 3 < T) loadK(t + 3);
      if (t + 2 < T) loadV(t + 2);

      // ---- finish chunk t: mask, softmax, repack, PV ----
      const int kv0 = (4 * t + grp) * KVBLK;
      if (kv0 <= q0w + 31) {
        if (kv0 + KVBLK - 1 > q0w) {
          const int qk = q0w + col - kv0;
#pragma unroll
          for (int r = 0; r < 16; ++r) {
            const int krow = (r & 3) + 8 * (r >> 2) + 4 * hi;
            st_cur[r] = (krow <= qk) ? st_cur[r] : -1e30f;
          }
        }

        float t8[8];
#pragma unroll
        for (int r = 0; r < 8; ++r) t8[r] = fmaxf(st_cur[r], st_cur[r + 8]);
#pragma unroll
        for (int r = 0; r < 4; ++r) t8[r] = fmaxf(t8[r], t8[r + 4]);
        const float pmax = pair_max(fmaxf(fmaxf(t8[0], t8[1]), fmaxf(t8[2], t8[3])));

        if (!__all(pmax <= m + 11.0f)) {   // T13 defer-max
          const float mnew = fmaxf(m, pmax);
          const float al = __builtin_amdgcn_exp2f(m - mnew);
          m = mnew;
          l *= al;
#pragma unroll
          for (int r = 0; r < 16; ++r) {
            const int row = (r & 3) + 8 * (r >> 2) + 4 * hi;
            const float ar = lane_bcast(row, al);
            o0[r] *= ar; o1[r] *= ar; o2[r] *= ar; o3[r] *= ar;
          }
        }

        float s4[4] = {0.f, 0.f, 0.f, 0.f};
#pragma unroll
        for (int r = 0; r < 16; ++r) {
          st_cur[r] = __builtin_amdgcn_exp2f(st_cur[r] - m);
          s4[r & 3] += st_cur[r];
        }
        l += pair_sum((s4[0] + s4[1]) + (s4[2] + s4[3]));

        // P -> A-fragments (pack + 4 cross-half shuffles)
        unsigned cw[8];
#pragma unroll
        for (int i = 0; i < 8; ++i) cw[i] = pack2(st_cur[2 * i], st_cur[2 * i + 1]);
        const unsigned x1 = (unsigned)__shfl_xor((int)(hi ? cw[0] : cw[2]), 32);
        const unsigned x2 = (unsigned)__shfl_xor((int)(hi ? cw[1] : cw[3]), 32);
        const unsigned x3 = (unsigned)__shfl_xor((int)(hi ? cw[4] : cw[6]), 32);
        const unsigned x4 = (unsigned)__shfl_xor((int)(hi ? cw[5] : cw[7]), 32);
        union { unsigned u[4]; bf16x8 v; } pa0, pa1;
        pa0.u[0] = hi ? x1 : cw[0];  pa0.u[1] = hi ? x2 : cw[1];
        pa0.u[2] = hi ? cw[2] : x1;  pa0.u[3] = hi ? cw[3] : x2;
        pa1.u[0] = hi ? x3 : cw[4];  pa1.u[1] = hi ? x4 : cw[5];
        pa1.u[2] = hi ? cw[6] : x3;  pa1.u[3] = hi ? cw[7] : x4;

        const char* vb = (const char*)&Vt[t & 1][grp][0];
        __builtin_amdgcn_s_setprio(1);
#pragma unroll
        for (int ks = 0; ks < 2; ++ks) {
          const bf16x8 pa = ks ? pa1.v : pa0.v;
#define PV_STEP(ovar, dt) { \
          bf16x8 vf = *(const bf16x8*)(vb + ((((dt)*32 + col) * 64 + ks * 32 + hi * 16) ^ vswz)); \
          ovar = mfma32(pa, vf, ovar); }
          PV_STEP(o0, 0) PV_STEP(o1, 1) PV_STEP(o2, 2) PV_STEP(o3, 3)
#undef PV_STEP
        }
        __builtin_amdgcn_s_setprio(0);
      }
      pipeline_barrier();
      st_cur = stn;
    }

    // ---- merge 4 key-group partials: (1->0, 3->2) in parallel, then (2->0) ----
    float* ob  = reinterpret_cast<float*>(&Klds[0][0][0]); // 16384 floats: region r at r*8192
    float* mlb = reinterpret_cast<float*>(&Vt[0][0][0]);   // region r at r*512
    float f0 = 1.f, f1 = 0.f;
    {
      const int src  = grp & 1;               // groups 1,3 are sources
      float* obr = ob  + (grp >> 1) * 8192;
      float* mlr = mlb + (grp >> 1) * 512;
      if (src) {
        mlr[wq * 128 + lane] = m;
        mlr[wq * 128 + 64 + lane] = l;
#pragma unroll
        for (int r = 0; r < 16; ++r) {
          obr[wq * 1024 + r * 64 + lane] = o0[r];
          obr[4096 + wq * 1024 + r * 64 + lane] = o1[r];
        }
      }
      __syncthreads();
      if (!src) {
        const float m1 = mlr[wq * 128 + lane];
        const float l1 = mlr[wq * 128 + 64 + lane];
        const float mS = fmaxf(m, m1);
        f0 = __builtin_amdgcn_exp2f(m - mS);
        f1 = __builtin_amdgcn_exp2f(m1 - mS);
        m = mS;
        l = l * f0 + l1 * f1;
#pragma unroll
        for (int r = 0; r < 16; ++r) {
          const int row = (r & 3) + 8 * (r >> 2) + 4 * hi;
          const float a0 = lane_bcast(row, f0), a1 = lane_bcast(row, f1);
          o0[r] = o0[r] * a0 + obr[wq * 1024 + r * 64 + lane] * a1;
          o1[r] = o1[r] * a0 + obr[4096 + wq * 1024 + r * 64 + lane] * a1;
        }
      }
      __syncthreads();
      if (src) {
#pragma unroll
        for (int r = 0; r < 16; ++r) {
          obr[wq * 1024 + r * 64 + lane] = o2[r];
          obr[4096 + wq * 1024 + r * 64 + lane] = o3[r];
        }
      }
      __syncthreads();
      if (!src) {
#pragma unroll
        for (int r = 0; r < 16; ++r) {
          const int row = (r & 3) + 8 * (r >> 2) + 4 * hi;
          const float a0 = lane_bcast(row, f0), a1 = lane_bcast(row, f1);
          o2[r] = o2[r] * a0 + obr[wq * 1024 + r * 64 + lane] * a1;
          o3[r] = o3[r] * a0 + obr[4096 + wq * 1024 + r * 64 + lane] * a1;
        }
      }
      __syncthreads();
    }
    {
      if (grp == 2) {
        mlb[wq * 128 + lane] = m;
        mlb[wq * 128 + 64 + lane] = l;
#pragma unroll
        for (int r = 0; r < 16; ++r) {
          ob[wq * 1024 + r * 64 + lane] = o0[r];
          ob[4096 + wq * 1024 + r * 64 + lane] = o1[r];
        }
      }
      __syncthreads();
      if (grp == 0) {
        const float m1 = mlb[wq * 128 + lane];
        const float l1 = mlb[wq * 128 + 64 + lane];
        const float mS = fmaxf(m, m1);
        f0 = __builtin_amdgcn_exp2f(m - mS);
        f1 = __builtin_amdgcn_exp2f(m1 - mS);
        l = l * f0 + l1 * f1;
#pragma unroll
        for (int r = 0; r < 16; ++r) {
          const int row = (r & 3) + 8 * (r >> 2) + 4 * hi;
          const float a0 = lane_bcast(row, f0), a1 = lane_bcast(row, f1);
          o0[r] = o0[r] * a0 + ob[wq * 1024 + r * 64 + lane] * a1;
          o1[r] = o1[r] * a0 + ob[4096 + wq * 1024 + r * 64 + lane] * a1;
        }
      }
      __syncthreads();
      if (grp == 2) {
#pragma unroll
        for (int r = 0; r < 16; ++r) {
          ob[wq * 1024 + r * 64 + lane] = o2[r];
          ob[4096 + wq * 1024 + r * 64 + lane] = o3[r];
        }
      }
      __syncthreads();
      if (grp == 0) {
#pragma unroll
        for (int r = 0; r < 16; ++r) {
          const int row = (r & 3) + 8 * (r >> 2) + 4 * hi;
          const float a0 = lane_bcast(row, f0), a1 = lane_bcast(row, f1);
          o2[r] = o2[r] * a0 + ob[wq * 1024 + r * 64 + lane] * a1;
          o3[r] = o3[r] * a0 + ob[4096 + wq * 1024 + r * 64 + lane] * a1;
        }
        // ---- epilogue: store ----
        const float linv = 1.0f / l;
#pragma unroll
        for (int r = 0; r < 16; ++r) {
          const int row = (r & 3) + 8 * (r >> 2) + 4 * hi;
          const float lr = lane_bcast(row, linv);
          float* op = O + base + (size_t)(q0w + row) * RS + col;
          op[0]  = o0[r] * lr;
          op[32] = o1[r] * lr;
          op[64] = o2[r] * lr;
          op[96] = o3[r] * lr;
        }
      }
    }
    __syncthreads();   // protect merge scratch before next tile's staging
  }
}

} // namespace

extern "C" void kernel_launch(void* const* d_in, const int* /*in_sizes*/, int /*n_in*/,
                              void* d_out, int /*out_size*/, void* /*d_ws*/, size_t /*ws_size*/,
                              hipStream_t stream) {
  const float* q = (const float*)d_in[0];
  const float* k = (const float*)d_in[1];
  const float* v = (const float*)d_in[2];
  float* o = (float*)d_out;
  dim3 grid(256);    // 1 block/CU (128 KB LDS), all blocks = 17 supersteps
  dim3 blk(1024);
  hipLaunchKernelGGL(fa_fwd, grid, blk, 0, stream, q, k, v, o);
}

// Round 4
// 307.935 us; speedup vs baseline: 1.6850x; 1.6850x over previous
//
#include <hip/hip_runtime.h>
#include <hip/hip_bf16.h>

namespace {

constexpr int Bn = 2, Sn = 2048, Hn = 16, Dn = 128;
constexpr int QBLK = 128;   // 4 q-waves x 32 queries
constexpr int KVBLK = 32;   // keys per chunk; superstep = 2 chunks (even/odd group)
constexpr int RS = Hn * Dn; // 2048 floats
constexpr float QSCALE = 0.08838834764831845f * 1.4426950408889634f; // 1/sqrt(D)*log2(e)

// workspace layout: [0,2048) flags (512 ints); data at 4096 B.
// per tile: 16384 floats O-partial + 128 m + 128 l, padded to 16896 floats.
constexpr size_t WS_DATA_OFF = 1024;        // in floats
constexpr size_t WS_TILE_STRIDE = 16896;    // in floats
constexpr size_t WS_NEED = 4096 + 512 * WS_TILE_STRIDE * 4;

typedef __bf16 bf16x8 __attribute__((ext_vector_type(8)));
typedef __bf16 bf16x2 __attribute__((ext_vector_type(2)));
typedef float  f32x16 __attribute__((ext_vector_type(16)));

__device__ __forceinline__ f32x16 mfma32(bf16x8 a, bf16x8 b, f32x16 c) {
  return __builtin_amdgcn_mfma_f32_32x32x16_bf16(a, b, c, 0, 0, 0);
}
__device__ __forceinline__ unsigned pack2(float a, float b) {
  union { __bf16 h[2]; unsigned u; } r;
  r.h[0] = (__bf16)a; r.h[1] = (__bf16)b;
  return r.u;
}
__device__ __forceinline__ float pair_max(float x) { return fmaxf(x, __shfl_xor(x, 32)); }
__device__ __forceinline__ float pair_sum(float x) { return x + __shfl_xor(x, 32); }
__device__ __forceinline__ float f4e(const float4& v, int j) {
  return j == 0 ? v.x : j == 1 ? v.y : j == 2 ? v.z : v.w;
}
__device__ __forceinline__ float lane_bcast(int row, float v) {
  return __uint_as_float(__builtin_amdgcn_ds_bpermute(row * 4, __float_as_uint(v)));
}

// lgkm-only barrier: publish LDS, leave register-destined global prefetches in flight.
__device__ __forceinline__ void pipeline_barrier() {
  __builtin_amdgcn_sched_barrier(0);
  asm volatile("s_waitcnt lgkmcnt(0)" ::: "memory");
  __builtin_amdgcn_s_barrier();
  __builtin_amdgcn_sched_barrier(0);
}

// ============================================================================
// Split-KV balanced kernel: 512 blocks x 512 threads, 2 blocks/CU (80 KB LDS).
// Each tile qt's KV range is split at 64*(qt+1). Block roles per pair p:
//   role0 (X): L(15-p) then U(p)   -> (16-p)+(p+1) = 17 supersteps
//   role1 (Y): U(15-p) then L(p)   -> 17 supersteps
// Every block = exactly 17 supersteps -> no solo phase, constant 16 waves/CU.
// Cross-block merge per tile through ws: role0 publishes (O,m,l) + release
// flag; role1 acquire-spins (all 512 blocks co-resident -> deadlock-free),
// merges in-register, stores final O. Inner per-wave code = verified R1.
// NOTE: 1024-thread variant is impossible: regsPerBlock=131072 caps 1024-thread
// blocks at 128 regs/thread -> massive spill (R2/R3 evidence, 64 VGPR + 750 MB
// scratch writes). 512-thread blocks get 256/thread and compile at 128 VGPR.
// ============================================================================
__global__ __launch_bounds__(512)
void fa_fwd_split(const float* __restrict__ Q, const float* __restrict__ K,
                  const float* __restrict__ V, float* __restrict__ O,
                  float* __restrict__ WS)
{
  __shared__ __align__(16) __bf16 Klds[6][KVBLK * 128]; // 48 KB, ring by chunk %6
  __shared__ __align__(16) __bf16 Vt[4][128 * KVBLK];   // 32 KB, ring by chunk &3
  __shared__ int s_old;

  const int tid  = threadIdx.x;
  const int lane = tid & 63;
  const int wave = tid >> 6;
  const int col  = lane & 31;
  const int hi   = lane >> 5;
  const int grp  = wave >> 2;   // 0: even chunks, 1: odd chunks
  const int wq   = wave & 3;

  // mapping: 4 heads per XCD; pair partner (bid, bid+256) co-resident, role flips
  const int xcd  = (int)blockIdx.x & 7;
  const int s    = (int)blockIdx.x >> 3;    // 0..63
  const int hidx = xcd * 4 + (s & 3);       // 0..31
  const int b    = hidx >> 4, h = hidx & 15;
  const int pr   = (s >> 2) & 7;            // pair 0..7
  const int role = (s >> 2) >> 3;           // 0 = writer, 1 = merger
  const size_t base = ((size_t)b * Sn) * RS + (size_t)h * Dn;

  // staging coords: threads 0-255 even chunk of superstep, 256-511 odd
  const int sthalf = tid >> 8, ht = tid & 255;
  const int skey = ht >> 3, sd = (ht & 7) * 16;
  const int vkey = (ht & 15) * 2, vd = (ht >> 4) * 8;

  float4 kr[4], vr[4];
  auto loadK = [&](int ss) {
    const int kv0 = (2 * ss + sthalf) * KVBLK;
    const float* kp = K + base + (size_t)(kv0 + skey) * RS + sd;
#pragma unroll
    for (int i = 0; i < 4; ++i) kr[i] = *(const float4*)(kp + 4 * i);
  };
  auto loadV = [&](int ss) {
    const int kv0 = (2 * ss + sthalf) * KVBLK;
    const float* vp = V + base + (size_t)(kv0 + vkey) * RS + vd;
    vr[0] = *(const float4*)(vp);
    vr[1] = *(const float4*)(vp + 4);
    vr[2] = *(const float4*)(vp + RS);
    vr[3] = *(const float4*)(vp + RS + 4);
  };
  auto stageK = [&](int ss) {
    char* kb = (char*)&Klds[(2 * ss + sthalf) % 6][0];
    const int kbase = skey * 256 + sd * 2;
    const int kswz  = (skey & 7) << 4;
#pragma unroll
    for (int i = 0; i < 2; ++i) {
      bf16x8 f;
      f[0] = (__bf16)kr[2*i].x;   f[1] = (__bf16)kr[2*i].y;
      f[2] = (__bf16)kr[2*i].z;   f[3] = (__bf16)kr[2*i].w;
      f[4] = (__bf16)kr[2*i+1].x; f[5] = (__bf16)kr[2*i+1].y;
      f[6] = (__bf16)kr[2*i+1].z; f[7] = (__bf16)kr[2*i+1].w;
      *(bf16x8*)(kb + ((kbase + 16 * i) ^ kswz)) = f;
    }
  };
  auto stageV = [&](int ss) {
    char* vb = (char*)&Vt[(2 * ss + sthalf) & 3][0];
#pragma unroll
    for (int j = 0; j < 8; ++j) {
      const int d = vd + j;
      bf16x2 w;
      w[0] = (__bf16)f4e(vr[j >> 2], j & 3);
      w[1] = (__bf16)f4e(vr[2 + (j >> 2)], j & 3);
      const int addr = (d * 64 + vkey * 2) ^ ((d & 3) << 4) ^ (((d >> 3) & 1) << 6);
      *(bf16x2*)(vb + addr) = w;
    }
  };

  const int cswz = (col & 7) << 4;
  const int vswz = ((col & 3) << 4) ^ (((col >> 3) & 1) << 6);

#pragma unroll 1
  for (int half = 0; half < 2; ++half) {
    const int qt = half ? pr : (15 - pr);
    const int Th = half ? (pr + 1) : (16 - pr);  // supersteps in this half
    const int lower = (role == half);            // role0.h0 / role1.h1 take lower KV
    const int t0 = lower ? 0 : Th;
    const int t1 = t0 + Th;
    const int q0w = qt * QBLK + wq * 32;

    // ---- Q fragments, scaled ----
    bf16x8 qf[8];
    {
      const float* qp = Q + base + (size_t)(q0w + col) * RS + hi * 8;
#pragma unroll
      for (int kk = 0; kk < 8; ++kk) {
        float4 a = *(const float4*)(qp + kk * 16);
        float4 c2 = *(const float4*)(qp + kk * 16 + 4);
        bf16x8 f;
        f[0] = (__bf16)(a.x * QSCALE);  f[1] = (__bf16)(a.y * QSCALE);
        f[2] = (__bf16)(a.z * QSCALE);  f[3] = (__bf16)(a.w * QSCALE);
        f[4] = (__bf16)(c2.x * QSCALE); f[5] = (__bf16)(c2.y * QSCALE);
        f[6] = (__bf16)(c2.z * QSCALE); f[7] = (__bf16)(c2.w * QSCALE);
        qf[kk] = f;
      }
    }

    f32x16 o0 = {}, o1 = {}, o2 = {}, o3 = {};
    float m = -1e30f, l = 0.f;

    // ---- prologue ----
    loadK(t0); loadV(t0);
    stageK(t0);
    if (t0 + 1 < t1) loadK(t0 + 1);
    stageV(t0);
    if (t0 + 1 < t1) loadV(t0 + 1);
    if (t0 + 1 < t1) stageK(t0 + 1);
    if (t0 + 2 < t1) loadK(t0 + 2);
    pipeline_barrier();

    // S(t0)
    f32x16 st_cur = {};
    if ((2 * t0 + grp) * KVBLK <= q0w + 31) {
      const char* kb = (const char*)&Klds[(2 * t0 + grp) % 6][0];
      __builtin_amdgcn_s_setprio(1);
#pragma unroll
      for (int kk = 0; kk < 8; ++kk) {
        bf16x8 ka = *(const bf16x8*)(kb + ((col * 256 + kk * 32 + hi * 16) ^ cswz));
        st_cur = mfma32(ka, qf[kk], st_cur);
      }
      __builtin_amdgcn_s_setprio(0);
    }

#pragma unroll 1
    for (int t = t0; t < t1; ++t) {
      // ---- QK^T(t+1) fills the MFMA pipe while softmax(t) runs on VALU ----
      f32x16 stn = {};
      const int icn = 2 * (t + 1) + grp;
      if (t + 1 < t1 && icn * KVBLK <= q0w + 31) {
        const char* kb = (const char*)&Klds[icn % 6][0];
        __builtin_amdgcn_s_setprio(1);
#pragma unroll
        for (int kk = 0; kk < 8; ++kk) {
          bf16x8 ka = *(const bf16x8*)(kb + ((col * 256 + kk * 32 + hi * 16) ^ cswz));
          stn = mfma32(ka, qf[kk], stn);
        }
        __builtin_amdgcn_s_setprio(0);
      }

      // ---- stage next buffers (consume loads issued last iter), issue new loads ----
      if (t + 2 < t1) stageK(t + 2);
      if (t + 1 < t1) stageV(t + 1);
      if (t + 3 < t1) loadK(t + 3);
      if (t + 2 < t1) loadV(t + 2);

      // ---- finish chunk t: mask, softmax, repack, PV ----
      const int kv0 = (2 * t + grp) * KVBLK;
      if (kv0 <= q0w + 31) {
        if (kv0 + KVBLK - 1 > q0w) {
          const int qk = q0w + col - kv0;
#pragma unroll
          for (int r = 0; r < 16; ++r) {
            const int krow = (r & 3) + 8 * (r >> 2) + 4 * hi;
            st_cur[r] = (krow <= qk) ? st_cur[r] : -1e30f;
          }
        }

        float t8[8];
#pragma unroll
        for (int r = 0; r < 8; ++r) t8[r] = fmaxf(st_cur[r], st_cur[r + 8]);
#pragma unroll
        for (int r = 0; r < 4; ++r) t8[r] = fmaxf(t8[r], t8[r + 4]);
        const float pmax = pair_max(fmaxf(fmaxf(t8[0], t8[1]), fmaxf(t8[2], t8[3])));

        if (!__all(pmax <= m + 11.0f)) {   // T13 defer-max
          const float mnew = fmaxf(m, pmax);
          const float al = __builtin_amdgcn_exp2f(m - mnew);
          m = mnew;
          l *= al;
#pragma unroll
          for (int r = 0; r < 16; ++r) {
            const int row = (r & 3) + 8 * (r >> 2) + 4 * hi;
            const float ar = lane_bcast(row, al);
            o0[r] *= ar; o1[r] *= ar; o2[r] *= ar; o3[r] *= ar;
          }
        }

        float s4[4] = {0.f, 0.f, 0.f, 0.f};
#pragma unroll
        for (int r = 0; r < 16; ++r) {
          st_cur[r] = __builtin_amdgcn_exp2f(st_cur[r] - m);
          s4[r & 3] += st_cur[r];
        }
        l += pair_sum((s4[0] + s4[1]) + (s4[2] + s4[3]));

        // P -> A-fragments (pack + 4 cross-half shuffles)
        unsigned cw[8];
#pragma unroll
        for (int i = 0; i < 8; ++i) cw[i] = pack2(st_cur[2 * i], st_cur[2 * i + 1]);
        const unsigned x1 = (unsigned)__shfl_xor((int)(hi ? cw[0] : cw[2]), 32);
        const unsigned x2 = (unsigned)__shfl_xor((int)(hi ? cw[1] : cw[3]), 32);
        const unsigned x3 = (unsigned)__shfl_xor((int)(hi ? cw[4] : cw[6]), 32);
        const unsigned x4 = (unsigned)__shfl_xor((int)(hi ? cw[5] : cw[7]), 32);
        union { unsigned u[4]; bf16x8 v; } pa0, pa1;
        pa0.u[0] = hi ? x1 : cw[0];  pa0.u[1] = hi ? x2 : cw[1];
        pa0.u[2] = hi ? cw[2] : x1;  pa0.u[3] = hi ? cw[3] : x2;
        pa1.u[0] = hi ? x3 : cw[4];  pa1.u[1] = hi ? x4 : cw[5];
        pa1.u[2] = hi ? cw[6] : x3;  pa1.u[3] = hi ? cw[7] : x4;

        const char* vb = (const char*)&Vt[(2 * t + grp) & 3][0];
        __builtin_amdgcn_s_setprio(1);
#pragma unroll
        for (int ks = 0; ks < 2; ++ks) {
          const bf16x8 pa = ks ? pa1.v : pa0.v;
#define PV_STEP(ovar, dt) { \
          bf16x8 vf = *(const bf16x8*)(vb + ((((dt)*32 + col) * 64 + ks * 32 + hi * 16) ^ vswz)); \
          ovar = mfma32(pa, vf, ovar); }
          PV_STEP(o0, 0) PV_STEP(o1, 1) PV_STEP(o2, 2) PV_STEP(o3, 3)
#undef PV_STEP
        }
        __builtin_amdgcn_s_setprio(0);
      }
      pipeline_barrier();
      st_cur = stn;
    }

    // ---- merge grp1 -> grp0 (LDS scratch over K/V rings) ----
    float* ob  = reinterpret_cast<float*>(&Klds[0][0]);   // 8192 floats (32 KB)
    float* mlb = reinterpret_cast<float*>(&Vt[0][0]);
    if (grp == 1) {
      mlb[wq * 128 + lane] = m;
      mlb[wq * 128 + 64 + lane] = l;
#pragma unroll
      for (int r = 0; r < 16; ++r) {
        ob[wq * 1024 + r * 64 + lane] = o0[r];
        ob[4096 + wq * 1024 + r * 64 + lane] = o1[r];
      }
    }
    __syncthreads();
    float f0 = 1.f, f1 = 0.f;
    if (grp == 0) {
      const float m1 = mlb[wq * 128 + lane];
      const float l1 = mlb[wq * 128 + 64 + lane];
      const float mS = fmaxf(m, m1);
      f0 = __builtin_amdgcn_exp2f(m - mS);
      f1 = __builtin_amdgcn_exp2f(m1 - mS);
      m = mS;
      l = l * f0 + l1 * f1;
#pragma unroll
      for (int r = 0; r < 16; ++r) {
        const int row = (r & 3) + 8 * (r >> 2) + 4 * hi;
        const float a0 = lane_bcast(row, f0), a1 = lane_bcast(row, f1);
        o0[r] = o0[r] * a0 + ob[wq * 1024 + r * 64 + lane] * a1;
        o1[r] = o1[r] * a0 + ob[4096 + wq * 1024 + r * 64 + lane] * a1;
      }
    }
    __syncthreads();
    if (grp == 1) {
#pragma unroll
      for (int r = 0; r < 16; ++r) {
        ob[wq * 1024 + r * 64 + lane] = o2[r];
        ob[4096 + wq * 1024 + r * 64 + lane] = o3[r];
      }
    }
    __syncthreads();
    if (grp == 0) {
#pragma unroll
      for (int r = 0; r < 16; ++r) {
        const int row = (r & 3) + 8 * (r >> 2) + 4 * hi;
        const float a0 = lane_bcast(row, f0), a1 = lane_bcast(row, f1);
        o2[r] = o2[r] * a0 + ob[wq * 1024 + r * 64 + lane] * a1;
        o3[r] = o3[r] * a0 + ob[4096 + wq * 1024 + r * 64 + lane] * a1;
      }
    }

    // ---- cross-block half merge through workspace ----
    const int tix = hidx * 16 + qt;
    float* W = WS + WS_DATA_OFF + (size_t)tix * WS_TILE_STRIDE;
    int* flag = reinterpret_cast<int*>(WS) + tix;

    if (role == 0) {
      // writer: publish unnormalized (O, m, l), release flag
      if (grp == 0) {
#pragma unroll
        for (int r = 0; r < 16; ++r) {
          const int row = (r & 3) + 8 * (r >> 2) + 4 * hi;
          float* wp = W + (size_t)(wq * 32 + row) * 128 + col;
          wp[0]  = o0[r];
          wp[32] = o1[r];
          wp[64] = o2[r];
          wp[96] = o3[r];
        }
        if (hi == 0) {
          W[16384 + wq * 32 + col] = m;
          W[16512 + wq * 32 + col] = l;
        }
      }
      __threadfence();
      __syncthreads();
      if (tid == 0)
        __hip_atomic_store(flag, 1, __ATOMIC_RELEASE, __HIP_MEMORY_SCOPE_AGENT);
    } else {
      // merger: acquire flag (all 512 blocks co-resident -> spin is safe)
      if (tid == 0) {
        while (__hip_atomic_load(flag, __ATOMIC_ACQUIRE, __HIP_MEMORY_SCOPE_AGENT) == 0)
          __builtin_amdgcn_s_sleep(8);
        s_old = 1;
      }
      __syncthreads();
      (void)__hip_atomic_load(flag, __ATOMIC_ACQUIRE, __HIP_MEMORY_SCOPE_AGENT);
      if (grp == 0) {
        const float mP = W[16384 + wq * 32 + col];
        const float lP = W[16512 + wq * 32 + col];
        const float mS = fmaxf(m, mP);
        const float g0 = __builtin_amdgcn_exp2f(m - mS);
        const float g1 = __builtin_amdgcn_exp2f(mP - mS);
        const float linv = 1.0f / (l * g0 + lP * g1);
        const float c0 = g0 * linv, c1 = g1 * linv;
#pragma unroll
        for (int r = 0; r < 16; ++r) {
          const int row = (r & 3) + 8 * (r >> 2) + 4 * hi;
          const float a0 = lane_bcast(row, c0), a1 = lane_bcast(row, c1);
          const float* wp = W + (size_t)(wq * 32 + row) * 128 + col;
          float* op = O + base + (size_t)(q0w + row) * RS + col;
          op[0]  = o0[r] * a0 + wp[0]  * a1;
          op[32] = o1[r] * a0 + wp[32] * a1;
          op[64] = o2[r] * a0 + wp[64] * a1;
          op[96] = o3[r] * a0 + wp[96] * a1;
        }
      }
    }
    __syncthreads();   // protect LDS scratch/rings before next half's staging
  }
}

// ============================================================================
// Fallback: verbatim R1 kernel (107 µs) if workspace is too small.
// ============================================================================
__global__ __launch_bounds__(512)
void fa_fwd_r1(const float* __restrict__ Q, const float* __restrict__ K,
               const float* __restrict__ V, float* __restrict__ O)
{
  __shared__ __align__(16) __bf16 Klds[6][KVBLK * 128];
  __shared__ __align__(16) __bf16 Vt[4][128 * KVBLK];

  const int tid  = threadIdx.x;
  const int lane = tid & 63;
  const int wave = tid >> 6;
  const int col  = lane & 31;
  const int hi   = lane >> 5;
  const int grp  = wave >> 2;
  const int wq   = wave & 3;

  const int xcd  = (int)blockIdx.x & 7;
  const int s    = (int)blockIdx.x >> 3;
  const int hidx = xcd * 4 + (s & 3);
  const int b    = hidx >> 4, h = hidx & 15;
  const int s2   = s >> 2;
  const int qt   = (s < 32) ? (15 - s2) : (s2 - 8);
  const int q0w  = qt * QBLK + wq * 32;
  const int T    = 2 * (qt + 1);
  const size_t base = ((size_t)b * Sn) * RS + (size_t)h * Dn;

  const int sthalf = tid >> 8, ht = tid & 255;
  const int skey = ht >> 3, sd = (ht & 7) * 16;
  const int vkey = (ht & 15) * 2, vd = (ht >> 4) * 8;

  float4 kr[4], vr[4];
  auto loadK = [&](int ss) {
    const int kv0 = (2 * ss + sthalf) * KVBLK;
    const float* kp = K + base + (size_t)(kv0 + skey) * RS + sd;
#pragma unroll
    for (int i = 0; i < 4; ++i) kr[i] = *(const float4*)(kp + 4 * i);
  };
  auto loadV = [&](int ss) {
    const int kv0 = (2 * ss + sthalf) * KVBLK;
    const float* vp = V + base + (size_t)(kv0 + vkey) * RS + vd;
    vr[0] = *(const float4*)(vp);
    vr[1] = *(const float4*)(vp + 4);
    vr[2] = *(const float4*)(vp + RS);
    vr[3] = *(const float4*)(vp + RS + 4);
  };
  auto stageK = [&](int ss) {
    char* kb = (char*)&Klds[(2 * ss + sthalf) % 6][0];
    const int kbase = skey * 256 + sd * 2;
    const int kswz  = (skey & 7) << 4;
#pragma unroll
    for (int i = 0; i < 2; ++i) {
      bf16x8 f;
      f[0] = (__bf16)kr[2*i].x;   f[1] = (__bf16)kr[2*i].y;
      f[2] = (__bf16)kr[2*i].z;   f[3] = (__bf16)kr[2*i].w;
      f[4] = (__bf16)kr[2*i+1].x; f[5] = (__bf16)kr[2*i+1].y;
      f[6] = (__bf16)kr[2*i+1].z; f[7] = (__bf16)kr[2*i+1].w;
      *(bf16x8*)(kb + ((kbase + 16 * i) ^ kswz)) = f;
    }
  };
  auto stageV = [&](int ss) {
    char* vb = (char*)&Vt[(2 * ss + sthalf) & 3][0];
#pragma unroll
    for (int j = 0; j < 8; ++j) {
      const int d = vd + j;
      bf16x2 w;
      w[0] = (__bf16)f4e(vr[j >> 2], j & 3);
      w[1] = (__bf16)f4e(vr[2 + (j >> 2)], j & 3);
      const int addr = (d * 64 + vkey * 2) ^ ((d & 3) << 4) ^ (((d >> 3) & 1) << 6);
      *(bf16x2*)(vb + addr) = w;
    }
  };

  const int cswz = (col & 7) << 4;
  const int vswz = ((col & 3) << 4) ^ (((col >> 3) & 1) << 6);

  bf16x8 qf[8];
  {
    const float* qp = Q + base + (size_t)(q0w + col) * RS + hi * 8;
#pragma unroll
    for (int kk = 0; kk < 8; ++kk) {
      float4 a = *(const float4*)(qp + kk * 16);
      float4 c2 = *(const float4*)(qp + kk * 16 + 4);
      bf16x8 f;
      f[0] = (__bf16)(a.x * QSCALE);  f[1] = (__bf16)(a.y * QSCALE);
      f[2] = (__bf16)(a.z * QSCALE);  f[3] = (__bf16)(a.w * QSCALE);
      f[4] = (__bf16)(c2.x * QSCALE); f[5] = (__bf16)(c2.y * QSCALE);
      f[6] = (__bf16)(c2.z * QSCALE); f[7] = (__bf16)(c2.w * QSCALE);
      qf[kk] = f;
    }
  }

  f32x16 o0 = {}, o1 = {}, o2 = {}, o3 = {};
  float m = -1e30f, l = 0.f;

  loadK(0); loadV(0);
  stageK(0);
  loadK(1);
  stageV(0);
  loadV(1);
  stageK(1);
  if (2 < T) loadK(2);
  pipeline_barrier();

  f32x16 st_cur = {};
  if (grp * KVBLK <= q0w + 31) {
    const char* kb = (const char*)&Klds[grp][0];
    __builtin_amdgcn_s_setprio(1);
#pragma unroll
    for (int kk = 0; kk < 8; ++kk) {
      bf16x8 ka = *(const bf16x8*)(kb + ((col * 256 + kk * 32 + hi * 16) ^ cswz));
      st_cur = mfma32(ka, qf[kk], st_cur);
    }
    __builtin_amdgcn_s_setprio(0);
  }

#pragma unroll 1
  for (int t = 0; t < T; ++t) {
    f32x16 stn = {};
    const int icn = 2 * (t + 1) + grp;
    if (t + 1 < T && icn * KVBLK <= q0w + 31) {
      const char* kb = (const char*)&Klds[icn % 6][0];
      __builtin_amdgcn_s_setprio(1);
#pragma unroll
      for (int kk = 0; kk < 8; ++kk) {
        bf16x8 ka = *(const bf16x8*)(kb + ((col * 256 + kk * 32 + hi * 16) ^ cswz));
        stn = mfma32(ka, qf[kk], stn);
      }
      __builtin_amdgcn_s_setprio(0);
    }

    if (t + 2 < T) stageK(t + 2);
    if (t + 1 < T) stageV(t + 1);
    if (t + 3 < T) loadK(t + 3);
    if (t + 2 < T) loadV(t + 2);

    const int kv0 = (2 * t + grp) * KVBLK;
    if (kv0 <= q0w + 31) {
      if (kv0 + KVBLK - 1 > q0w) {
        const int qk = q0w + col - kv0;
#pragma unroll
        for (int r = 0; r < 16; ++r) {
          const int krow = (r & 3) + 8 * (r >> 2) + 4 * hi;
          st_cur[r] = (krow <= qk) ? st_cur[r] : -1e30f;
        }
      }

      float t8[8];
#pragma unroll
      for (int r = 0; r < 8; ++r) t8[r] = fmaxf(st_cur[r], st_cur[r + 8]);
#pragma unroll
      for (int r = 0; r < 4; ++r) t8[r] = fmaxf(t8[r], t8[r + 4]);
      const float pmax = pair_max(fmaxf(fmaxf(t8[0], t8[1]), fmaxf(t8[2], t8[3])));

      if (!__all(pmax <= m + 11.0f)) {
        const float mnew = fmaxf(m, pmax);
        const float al = __builtin_amdgcn_exp2f(m - mnew);
        m = mnew;
        l *= al;
#pragma unroll
        for (int r = 0; r < 16; ++r) {
          const int row = (r & 3) + 8 * (r >> 2) + 4 * hi;
          const float ar = lane_bcast(row, al);
          o0[r] *= ar; o1[r] *= ar; o2[r] *= ar; o3[r] *= ar;
        }
      }

      float s4[4] = {0.f, 0.f, 0.f, 0.f};
#pragma unroll
      for (int r = 0; r < 16; ++r) {
        st_cur[r] = __builtin_amdgcn_exp2f(st_cur[r] - m);
        s4[r & 3] += st_cur[r];
      }
      l += pair_sum((s4[0] + s4[1]) + (s4[2] + s4[3]));

      unsigned cw[8];
#pragma unroll
      for (int i = 0; i < 8; ++i) cw[i] = pack2(st_cur[2 * i], st_cur[2 * i + 1]);
      const unsigned x1 = (unsigned)__shfl_xor((int)(hi ? cw[0] : cw[2]), 32);
      const unsigned x2 = (unsigned)__shfl_xor((int)(hi ? cw[1] : cw[3]), 32);
      const unsigned x3 = (unsigned)__shfl_xor((int)(hi ? cw[4] : cw[6]), 32);
      const unsigned x4 = (unsigned)__shfl_xor((int)(hi ? cw[5] : cw[7]), 32);
      union { unsigned u[4]; bf16x8 v; } pa0, pa1;
      pa0.u[0] = hi ? x1 : cw[0];  pa0.u[1] = hi ? x2 : cw[1];
      pa0.u[2] = hi ? cw[2] : x1;  pa0.u[3] = hi ? cw[3] : x2;
      pa1.u[0] = hi ? x3 : cw[4];  pa1.u[1] = hi ? x4 : cw[5];
      pa1.u[2] = hi ? cw[6] : x3;  pa1.u[3] = hi ? cw[7] : x4;

      const char* vb = (const char*)&Vt[(2 * t + grp) & 3][0];
      __builtin_amdgcn_s_setprio(1);
#pragma unroll
      for (int ks = 0; ks < 2; ++ks) {
        const bf16x8 pa = ks ? pa1.v : pa0.v;
#define PV_STEP(ovar, dt) { \
        bf16x8 vf = *(const bf16x8*)(vb + ((((dt)*32 + col) * 64 + ks * 32 + hi * 16) ^ vswz)); \
        ovar = mfma32(pa, vf, ovar); }
        PV_STEP(o0, 0) PV_STEP(o1, 1) PV_STEP(o2, 2) PV_STEP(o3, 3)
#undef PV_STEP
      }
      __builtin_amdgcn_s_setprio(0);
    }
    pipeline_barrier();
    st_cur = stn;
  }

  float* ob  = reinterpret_cast<float*>(&Klds[0][0]);
  float* mlb = reinterpret_cast<float*>(&Vt[0][0]);
  if (grp == 1) {
    mlb[wq * 128 + lane] = m;
    mlb[wq * 128 + 64 + lane] = l;
#pragma unroll
    for (int r = 0; r < 16; ++r) {
      ob[wq * 1024 + r * 64 + lane] = o0[r];
      ob[4096 + wq * 1024 + r * 64 + lane] = o1[r];
    }
  }
  __syncthreads();
  float f0 = 1.f, f1 = 0.f;
  if (grp == 0) {
    const float m1 = mlb[wq * 128 + lane];
    const float l1 = mlb[wq * 128 + 64 + lane];
    const float mS = fmaxf(m, m1);
    f0 = __builtin_amdgcn_exp2f(m - mS);
    f1 = __builtin_amdgcn_exp2f(m1 - mS);
    l = l * f0 + l1 * f1;
#pragma unroll
    for (int r = 0; r < 16; ++r) {
      const int row = (r & 3) + 8 * (r >> 2) + 4 * hi;
      const float a0 = lane_bcast(row, f0), a1 = lane_bcast(row, f1);
      o0[r] = o0[r] * a0 + ob[wq * 1024 + r * 64 + lane] * a1;
      o1[r] = o1[r] * a0 + ob[4096 + wq * 1024 + r * 64 + lane] * a1;
    }
  }
  __syncthreads();
  if (grp == 1) {
#pragma unroll
    for (int r = 0; r < 16; ++r) {
      ob[wq * 1024 + r * 64 + lane] = o2[r];
      ob[4096 + wq * 1024 + r * 64 + lane] = o3[r];
    }
  }
  __syncthreads();
  if (grp == 0) {
#pragma unroll
    for (int r = 0; r < 16; ++r) {
      const int row = (r & 3) + 8 * (r >> 2) + 4 * hi;
      const float a0 = lane_bcast(row, f0), a1 = lane_bcast(row, f1);
      o2[r] = o2[r] * a0 + ob[wq * 1024 + r * 64 + lane] * a1;
      o3[r] = o3[r] * a0 + ob[4096 + wq * 1024 + r * 64 + lane] * a1;
    }
    const float linv = 1.0f / l;
#pragma unroll
    for (int r = 0; r < 16; ++r) {
      const int row = (r & 3) + 8 * (r >> 2) + 4 * hi;
      const float lr = lane_bcast(row, linv);
      float* op = O + base + (size_t)(q0w + row) * RS + col;
      op[0]  = o0[r] * lr;
      op[32] = o1[r] * lr;
      op[64] = o2[r] * lr;
      op[96] = o3[r] * lr;
    }
  }
}

} // namespace

extern "C" void kernel_launch(void* const* d_in, const int* /*in_sizes*/, int /*n_in*/,
                              void* d_out, int /*out_size*/, void* d_ws, size_t ws_size,
                              hipStream_t stream) {
  const float* q = (const float*)d_in[0];
  const float* k = (const float*)d_in[1];
  const float* v = (const float*)d_in[2];
  float* o = (float*)d_out;
  if (d_ws != nullptr && ws_size >= WS_NEED) {
    hipMemsetAsync(d_ws, 0, 4096, stream);   // zero the 512 tile flags (capture-safe)
    dim3 grid(512), blk(512);
    hipLaunchKernelGGL(fa_fwd_split, grid, blk, 0, stream, q, k, v, o, (float*)d_ws);
  } else {
    dim3 grid(512), blk(512);
    hipLaunchKernelGGL(fa_fwd_r1, grid, blk, 0, stream, q, k, v, o);
  }
}

// Round 5
// 104.179 us; speedup vs baseline: 4.9807x; 2.9558x over previous
//
#include <hip/hip_runtime.h>
#include <hip/hip_bf16.h>

namespace {

constexpr int Bn = 2, Sn = 2048, Hn = 16, Dn = 128;
constexpr int QBLK = 128;   // 2 groups x 4 waves x 32 queries
constexpr int KVBLK = 32;   // keys per chunk; superstep = 2 chunks (even/odd group)
constexpr int RS = Hn * Dn; // 2048 floats
constexpr float QSCALE = 0.08838834764831845f * 1.4426950408889634f; // 1/sqrt(D)*log2(e)

typedef __bf16 bf16x8 __attribute__((ext_vector_type(8)));
typedef __bf16 bf16x4 __attribute__((ext_vector_type(4)));
typedef float  f32x16 __attribute__((ext_vector_type(16)));

__device__ __forceinline__ f32x16 mfma32(bf16x8 a, bf16x8 b, f32x16 c) {
  return __builtin_amdgcn_mfma_f32_32x32x16_bf16(a, b, c, 0, 0, 0);
}
__device__ __forceinline__ unsigned pack2(float a, float b) {
  union { __bf16 h[2]; unsigned u; } r;
  r.h[0] = (__bf16)a; r.h[1] = (__bf16)b;
  return r.u;
}
// T12 primitive: lane<->lane^32 exchange on the VALU pipe (m255: 1.20x vs
// ds_bpermute) instead of __shfl_xor's LDS round-trip.
// permlane32_swap(a,b) -> ret0 = [a.lo | b.lo], ret1 = [a.hi | b.hi].
__device__ __forceinline__ float pair_max(float x, int hi) {
  auto r = __builtin_amdgcn_permlane32_swap(__float_as_uint(x), __float_as_uint(x), false, false);
  const float sw = __uint_as_float(hi ? r[0] : r[1]);
  return fmaxf(x, sw);
}
__device__ __forceinline__ float pair_sum(float x, int hi) {
  auto r = __builtin_amdgcn_permlane32_swap(__float_as_uint(x), __float_as_uint(x), false, false);
  const float sw = __uint_as_float(hi ? r[0] : r[1]);
  return x + sw;
}
__device__ __forceinline__ float f4e(const float4& v, int j) {
  return j == 0 ? v.x : j == 1 ? v.y : j == 2 ? v.z : v.w;
}
__device__ __forceinline__ float lane_bcast(int row, float v) {
  return __uint_as_float(__builtin_amdgcn_ds_bpermute(row * 4, __float_as_uint(v)));
}

// lgkm-only barrier: publish LDS, leave register-destined global prefetches in flight.
__device__ __forceinline__ void pipeline_barrier() {
  __builtin_amdgcn_sched_barrier(0);
  asm volatile("s_waitcnt lgkmcnt(0)" ::: "memory");
  __builtin_amdgcn_s_barrier();
  __builtin_amdgcn_sched_barrier(0);
}

// 512 blocks, ONE q-tile each; LDS = 80 KB exactly -> 2 blocks/CU.
// Mapping (verified): same-XCD heads, co-resident pair (bid, bid+256)
// = tiles (15-s2, s2) -> balanced per-CU work. Inner loop: QK^T(t+1) on the
// MFMA pipe, softmax(t)+PV(t) overlap on VALU. K ring-6, V ring-4.
// R5: cross-lane ops on the softmax critical chain moved from ds_bpermute
// (LDS, ~120cyc) to v_permlane32_swap (VALU); V-stage 8x b32 -> 4x b64.
__global__ __launch_bounds__(512)
void fa_fwd(const float* __restrict__ Q, const float* __restrict__ K,
            const float* __restrict__ V, float* __restrict__ O)
{
  __shared__ __align__(16) __bf16 Klds[6][KVBLK * 128]; // 48 KB, ring by chunk %6
  __shared__ __align__(16) __bf16 Vt[4][128 * KVBLK];   // 32 KB, ring by chunk &3

  const int tid  = threadIdx.x;
  const int lane = tid & 63;
  const int wave = tid >> 6;
  const int col  = lane & 31;
  const int hi   = lane >> 5;
  const int grp  = wave >> 2;   // 0: even chunks, 1: odd chunks
  const int wq   = wave & 3;

  const int xcd  = (int)blockIdx.x & 7;
  const int s    = (int)blockIdx.x >> 3;    // 0..63
  const int hidx = xcd * 4 + (s & 3);       // 0..31
  const int b    = hidx >> 4, h = hidx & 15;
  const int s2   = s >> 2;                  // 0..15
  const int qt   = (s < 32) ? (15 - s2) : (s2 - 8);
  const int q0w  = qt * QBLK + wq * 32;
  const int T    = 2 * (qt + 1);            // supersteps
  const size_t base = ((size_t)b * Sn) * RS + (size_t)h * Dn;

  // staging coords: threads 0-255 even chunk of superstep, 256-511 odd
  const int sthalf = tid >> 8, ht = tid & 255;
  const int skey = ht >> 3, sd = (ht & 7) * 16;
  const int vkey4 = (ht & 7) * 4, vd4 = (ht >> 3) * 4;

  float4 kr[4], vr[4];
  auto loadK = [&](int ss) {
    const int kv0 = (2 * ss + sthalf) * KVBLK;
    const float* kp = K + base + (size_t)(kv0 + skey) * RS + sd;
#pragma unroll
    for (int i = 0; i < 4; ++i) kr[i] = *(const float4*)(kp + 4 * i);
  };
  auto loadV = [&](int ss) {
    const int kv0 = (2 * ss + sthalf) * KVBLK;
    const float* vp = V + base + (size_t)(kv0 + vkey4) * RS + vd4;
#pragma unroll
    for (int i = 0; i < 4; ++i) vr[i] = *(const float4*)(vp + (size_t)i * RS);
  };
  auto stageK = [&](int ss) {
    char* kb = (char*)&Klds[(2 * ss + sthalf) % 6][0];
    const int kbase = skey * 256 + sd * 2;
    const int kswz  = (skey & 7) << 4;
#pragma unroll
    for (int i = 0; i < 2; ++i) {
      bf16x8 f;
      f[0] = (__bf16)kr[2*i].x;   f[1] = (__bf16)kr[2*i].y;
      f[2] = (__bf16)kr[2*i].z;   f[3] = (__bf16)kr[2*i].w;
      f[4] = (__bf16)kr[2*i+1].x; f[5] = (__bf16)kr[2*i+1].y;
      f[6] = (__bf16)kr[2*i+1].z; f[7] = (__bf16)kr[2*i+1].w;
      *(bf16x8*)(kb + ((kbase + 16 * i) ^ kswz)) = f;
    }
  };
  // V-stage: 4 keys x 4 d per thread -> 4x ds_write_b64 (was 8x b32).
  auto stageV = [&](int ss) {
    char* vb = (char*)&Vt[(2 * ss + sthalf) & 3][0];
    const int b6 = ((vd4 >> 3) & 1) << 6;
#pragma unroll
    for (int j = 0; j < 4; ++j) {
      bf16x4 w;
      w[0] = (__bf16)f4e(vr[0], j);
      w[1] = (__bf16)f4e(vr[1], j);
      w[2] = (__bf16)f4e(vr[2], j);
      w[3] = (__bf16)f4e(vr[3], j);
      const int addr = (((vd4 + j) * 64 + vkey4 * 2) ^ (j << 4)) ^ b6;
      *(bf16x4*)(vb + addr) = w;
    }
  };

  const int cswz = (col & 7) << 4;
  const int vswz = ((col & 3) << 4) ^ (((col >> 3) & 1) << 6);

  // ---- Q fragments, scaled ----
  bf16x8 qf[8];
  {
    const float* qp = Q + base + (size_t)(q0w + col) * RS + hi * 8;
#pragma unroll
    for (int kk = 0; kk < 8; ++kk) {
      float4 a = *(const float4*)(qp + kk * 16);
      float4 c2 = *(const float4*)(qp + kk * 16 + 4);
      bf16x8 f;
      f[0] = (__bf16)(a.x * QSCALE);  f[1] = (__bf16)(a.y * QSCALE);
      f[2] = (__bf16)(a.z * QSCALE);  f[3] = (__bf16)(a.w * QSCALE);
      f[4] = (__bf16)(c2.x * QSCALE); f[5] = (__bf16)(c2.y * QSCALE);
      f[6] = (__bf16)(c2.z * QSCALE); f[7] = (__bf16)(c2.w * QSCALE);
      qf[kk] = f;
    }
  }

  f32x16 o0 = {}, o1 = {}, o2 = {}, o3 = {};
  float m = -1e30f, l = 0.f;

  // ---- prologue: stage K(0),K(1),V(0); issue loads for loop t=0 ----
  loadK(0); loadV(0);
  stageK(0);
  loadK(1);
  stageV(0);
  loadV(1);
  stageK(1);
  if (2 < T) loadK(2);
  pipeline_barrier();           // K0,K1,V0 published

  // S(0)
  f32x16 st_cur = {};
  if (grp * KVBLK <= q0w + 31) {
    const char* kb = (const char*)&Klds[grp][0];
    __builtin_amdgcn_s_setprio(1);
#pragma unroll
    for (int kk = 0; kk < 8; ++kk) {
      bf16x8 ka = *(const bf16x8*)(kb + ((col * 256 + kk * 32 + hi * 16) ^ cswz));
      st_cur = mfma32(ka, qf[kk], st_cur);
    }
    __builtin_amdgcn_s_setprio(0);
  }

#pragma unroll 1
  for (int t = 0; t < T; ++t) {
    // ---- QK^T(t+1): fills the MFMA pipe while softmax(t) runs on VALU ----
    f32x16 stn = {};
    const int icn = 2 * (t + 1) + grp;
    if (t + 1 < T && icn * KVBLK <= q0w + 31) {
      const char* kb = (const char*)&Klds[icn % 6][0];
      __builtin_amdgcn_s_setprio(1);
#pragma unroll
      for (int kk = 0; kk < 8; ++kk) {
        bf16x8 ka = *(const bf16x8*)(kb + ((col * 256 + kk * 32 + hi * 16) ^ cswz));
        stn = mfma32(ka, qf[kk], stn);
      }
      __builtin_amdgcn_s_setprio(0);
    }

    // ---- stage next buffers (consume loads issued last iter), issue new loads ----
    if (t + 2 < T) stageK(t + 2);
    if (t + 1 < T) stageV(t + 1);
    if (t + 3 < T) loadK(t + 3);
    if (t + 2 < T) loadV(t + 2);

    // ---- finish chunk t: mask, softmax, repack, PV ----
    const int kv0 = (2 * t + grp) * KVBLK;
    if (kv0 <= q0w + 31) {
      if (kv0 + KVBLK - 1 > q0w) {
        const int qk = q0w + col - kv0;
#pragma unroll
        for (int r = 0; r < 16; ++r) {
          const int krow = (r & 3) + 8 * (r >> 2) + 4 * hi;
          st_cur[r] = (krow <= qk) ? st_cur[r] : -1e30f;
        }
      }

      float t8[8];
#pragma unroll
      for (int r = 0; r < 8; ++r) t8[r] = fmaxf(st_cur[r], st_cur[r + 8]);
#pragma unroll
      for (int r = 0; r < 4; ++r) t8[r] = fmaxf(t8[r], t8[r + 4]);
      const float pmax = pair_max(fmaxf(fmaxf(t8[0], t8[1]), fmaxf(t8[2], t8[3])), hi);

      if (!__all(pmax <= m + 11.0f)) {   // T13 defer-max
        const float mnew = fmaxf(m, pmax);
        const float al = __builtin_amdgcn_exp2f(m - mnew);
        m = mnew;
        l *= al;
#pragma unroll
        for (int r = 0; r < 16; ++r) {
          const int row = (r & 3) + 8 * (r >> 2) + 4 * hi;
          const float ar = lane_bcast(row, al);
          o0[r] *= ar; o1[r] *= ar; o2[r] *= ar; o3[r] *= ar;
        }
      }

      float s4[4] = {0.f, 0.f, 0.f, 0.f};
#pragma unroll
      for (int r = 0; r < 16; ++r) {
        st_cur[r] = __builtin_amdgcn_exp2f(st_cur[r] - m);
        s4[r & 3] += st_cur[r];
      }
      l += pair_sum((s4[0] + s4[1]) + (s4[2] + s4[3]), hi);

      // P -> A-fragments: 4 permlane32_swap, each yields BOTH output words:
      //   swap(cw0,cw2) = {[cw0.lo|cw2.lo], [cw0.hi|cw2.hi]} = {pa0.u0, pa0.u2}
      unsigned cw[8];
#pragma unroll
      for (int i = 0; i < 8; ++i) cw[i] = pack2(st_cur[2 * i], st_cur[2 * i + 1]);
      union { unsigned u[4]; bf16x8 v; } pa0, pa1;
      {
        auto s02 = __builtin_amdgcn_permlane32_swap(cw[0], cw[2], false, false);
        auto s13 = __builtin_amdgcn_permlane32_swap(cw[1], cw[3], false, false);
        auto s46 = __builtin_amdgcn_permlane32_swap(cw[4], cw[6], false, false);
        auto s57 = __builtin_amdgcn_permlane32_swap(cw[5], cw[7], false, false);
        pa0.u[0] = s02[0]; pa0.u[2] = s02[1];
        pa0.u[1] = s13[0]; pa0.u[3] = s13[1];
        pa1.u[0] = s46[0]; pa1.u[2] = s46[1];
        pa1.u[1] = s57[0]; pa1.u[3] = s57[1];
      }

      const char* vb = (const char*)&Vt[(2 * t + grp) & 3][0];
      __builtin_amdgcn_s_setprio(1);
#pragma unroll
      for (int ks = 0; ks < 2; ++ks) {
        const bf16x8 pa = ks ? pa1.v : pa0.v;
#define PV_STEP(ovar, dt) { \
        bf16x8 vf = *(const bf16x8*)(vb + ((((dt)*32 + col) * 64 + ks * 32 + hi * 16) ^ vswz)); \
        ovar = mfma32(pa, vf, ovar); }
        PV_STEP(o0, 0) PV_STEP(o1, 1) PV_STEP(o2, 2) PV_STEP(o3, 3)
#undef PV_STEP
      }
      __builtin_amdgcn_s_setprio(0);
    }
    pipeline_barrier();
    st_cur = stn;
  }

  // ---- merge group-1 partials into group-0 (LDS scratch over K/V buffers) ----
  float* ob  = reinterpret_cast<float*>(&Klds[0][0]);   // 8192 floats (32 KB)
  float* mlb = reinterpret_cast<float*>(&Vt[0][0]);
  if (grp == 1) {
    mlb[wq * 128 + lane] = m;
    mlb[wq * 128 + 64 + lane] = l;
#pragma unroll
    for (int r = 0; r < 16; ++r) {
      ob[wq * 1024 + r * 64 + lane] = o0[r];
      ob[4096 + wq * 1024 + r * 64 + lane] = o1[r];
    }
  }
  __syncthreads();
  float f0 = 1.f, f1 = 0.f;
  if (grp == 0) {
    const float m1 = mlb[wq * 128 + lane];
    const float l1 = mlb[wq * 128 + 64 + lane];
    const float mS = fmaxf(m, m1);
    f0 = __builtin_amdgcn_exp2f(m - mS);
    f1 = __builtin_amdgcn_exp2f(m1 - mS);
    l = l * f0 + l1 * f1;
#pragma unroll
    for (int r = 0; r < 16; ++r) {
      const int row = (r & 3) + 8 * (r >> 2) + 4 * hi;
      const float a0 = lane_bcast(row, f0), a1 = lane_bcast(row, f1);
      o0[r] = o0[r] * a0 + ob[wq * 1024 + r * 64 + lane] * a1;
      o1[r] = o1[r] * a0 + ob[4096 + wq * 1024 + r * 64 + lane] * a1;
    }
  }
  __syncthreads();
  if (grp == 1) {
#pragma unroll
    for (int r = 0; r < 16; ++r) {
      ob[wq * 1024 + r * 64 + lane] = o2[r];
      ob[4096 + wq * 1024 + r * 64 + lane] = o3[r];
    }
  }
  __syncthreads();
  if (grp == 0) {
#pragma unroll
    for (int r = 0; r < 16; ++r) {
      const int row = (r & 3) + 8 * (r >> 2) + 4 * hi;
      const float a0 = lane_bcast(row, f0), a1 = lane_bcast(row, f1);
      o2[r] = o2[r] * a0 + ob[wq * 1024 + r * 64 + lane] * a1;
      o3[r] = o3[r] * a0 + ob[4096 + wq * 1024 + r * 64 + lane] * a1;
    }
    // ---- epilogue: store ----
    const float linv = 1.0f / l;
#pragma unroll
    for (int r = 0; r < 16; ++r) {
      const int row = (r & 3) + 8 * (r >> 2) + 4 * hi;
      const float lr = lane_bcast(row, linv);
      float* op = O + base + (size_t)(q0w + row) * RS + col;
      op[0]  = o0[r] * lr;
      op[32] = o1[r] * lr;
      op[64] = o2[r] * lr;
      op[96] = o3[r] * lr;
    }
  }
}

} // namespace

extern "C" void kernel_launch(void* const* d_in, const int* /*in_sizes*/, int /*n_in*/,
                              void* d_out, int /*out_size*/, void* /*d_ws*/, size_t /*ws_size*/,
                              hipStream_t stream) {
  const float* q = (const float*)d_in[0];
  const float* k = (const float*)d_in[1];
  const float* v = (const float*)d_in[2];
  float* o = (float*)d_out;
  dim3 grid(Bn * Hn * (Sn / QBLK));   // 512 blocks, 2 per CU (80 KB LDS each)
  dim3 blk(512);
  hipLaunchKernelGGL(fa_fwd, grid, blk, 0, stream, q, k, v, o);
}

// Round 6
// 102.343 us; speedup vs baseline: 5.0700x; 1.0179x over previous
//
#include <hip/hip_runtime.h>
#include <hip/hip_bf16.h>

namespace {

constexpr int Bn = 2, Sn = 2048, Hn = 16, Dn = 128;
constexpr int QBLK = 128;   // 2 groups x 4 waves x 32 queries
constexpr int KVBLK = 32;   // keys per chunk; superstep = 2 chunks (even/odd group)
constexpr int RS = Hn * Dn; // 2048 floats
constexpr float QSCALE = 0.08838834764831845f * 1.4426950408889634f; // 1/sqrt(D)*log2(e)

// bf16 K/V images, pre-swizzled to the exact LDS chunk layout.
// 2048 chunks (2*16*64) x 8192 B each, K then V.
constexpr size_t IMG_BYTES = (size_t)Bn * Hn * 64 * 8192;   // 16 MB
constexpr size_t WS_NEED   = 2 * IMG_BYTES;                 // 32 MB

typedef __bf16 bf16x8 __attribute__((ext_vector_type(8)));
typedef __bf16 bf16x4 __attribute__((ext_vector_type(4)));
typedef float  f32x16 __attribute__((ext_vector_type(16)));

__device__ __forceinline__ f32x16 mfma32(bf16x8 a, bf16x8 b, f32x16 c) {
  return __builtin_amdgcn_mfma_f32_32x32x16_bf16(a, b, c, 0, 0, 0);
}
__device__ __forceinline__ unsigned pack2(float a, float b) {
  union { __bf16 h[2]; unsigned u; } r;
  r.h[0] = (__bf16)a; r.h[1] = (__bf16)b;
  return r.u;
}
// lane<->lane^32 exchange on the VALU pipe (T12 primitive).
__device__ __forceinline__ float pair_max(float x, int hi) {
  auto r = __builtin_amdgcn_permlane32_swap(__float_as_uint(x), __float_as_uint(x), false, false);
  const float sw = __uint_as_float(hi ? r[0] : r[1]);
  return fmaxf(x, sw);
}
__device__ __forceinline__ float pair_sum(float x, int hi) {
  auto r = __builtin_amdgcn_permlane32_swap(__float_as_uint(x), __float_as_uint(x), false, false);
  const float sw = __uint_as_float(hi ? r[0] : r[1]);
  return x + sw;
}
__device__ __forceinline__ float f4e(const float4& v, int j) {
  return j == 0 ? v.x : j == 1 ? v.y : j == 2 ? v.z : v.w;
}
__device__ __forceinline__ float lane_bcast(int row, float v) {
  return __uint_as_float(__builtin_amdgcn_ds_bpermute(row * 4, __float_as_uint(v)));
}

// async 16B global->LDS DMA (linear dest: uniform lds base + lane*16)
__device__ __forceinline__ void cp16(const char* g, char* l) {
  __builtin_amdgcn_global_load_lds(
      (const __attribute__((address_space(1))) void*)g,
      (__attribute__((address_space(3))) void*)l, 16, 0, 0);
}

// full barrier: DMA'd LDS + ds ops visible to all waves.
__device__ __forceinline__ void dma_barrier() {
  __builtin_amdgcn_sched_barrier(0);
  asm volatile("s_waitcnt vmcnt(0) lgkmcnt(0)" ::: "memory");
  __builtin_amdgcn_s_barrier();
  __builtin_amdgcn_sched_barrier(0);
}
// lgkm-only barrier (fallback kernel): leaves reg-destined prefetches in flight.
__device__ __forceinline__ void pipeline_barrier() {
  __builtin_amdgcn_sched_barrier(0);
  asm volatile("s_waitcnt lgkmcnt(0)" ::: "memory");
  __builtin_amdgcn_s_barrier();
  __builtin_amdgcn_sched_barrier(0);
}

// ============================================================================
// Pre-pass: fp32 K/V -> bf16 images in the EXACT swizzled LDS chunk layout.
// K image byte (per 8 KB chunk): key j, d-block (8 d's):
//   (j*256 + dblk*16) ^ ((j&7)<<4)        <- K[j][dblk*8..+7]
// V image byte: d, key-octet k0=koct*8:
//   (d*64 + koct*16) ^ ((d&3)<<4) ^ (((d>>3)&1)<<6)   <- V[k0..k0+7][d]
// ============================================================================
__global__ __launch_bounds__(256)
void prep_kv(const float* __restrict__ K, const float* __restrict__ V,
             __bf16* __restrict__ KI, __bf16* __restrict__ VI)
{
  const int gid  = (int)blockIdx.x * 256 + (int)threadIdx.x; // 0..2M
  const int half = gid >> 20;              // 0=K, 1=V
  const int id   = gid & ((1 << 20) - 1);  // 0..1M
  const int chunk = id >> 9;               // 0..2047
  const int rem   = id & 511;
  const int bh = chunk >> 6, c = chunk & 63;
  const int b = bh >> 4, h = bh & 15;
  if (half == 0) {
    const int key = rem >> 4, dblk = rem & 15;
    const float* src = K + ((size_t)b * Sn + (size_t)c * 32 + key) * RS + h * Dn + dblk * 8;
    float4 a  = *(const float4*)src;
    float4 c2 = *(const float4*)(src + 4);
    bf16x8 f;
    f[0] = (__bf16)a.x;  f[1] = (__bf16)a.y;  f[2] = (__bf16)a.z;  f[3] = (__bf16)a.w;
    f[4] = (__bf16)c2.x; f[5] = (__bf16)c2.y; f[6] = (__bf16)c2.z; f[7] = (__bf16)c2.w;
    char* dst = (char*)KI + (size_t)chunk * 8192 + ((key * 256 + dblk * 16) ^ ((key & 7) << 4));
    *(bf16x8*)dst = f;
  } else {
    const int d = rem >> 2, koct = rem & 3;
    const float* src = V + ((size_t)b * Sn + (size_t)c * 32 + koct * 8) * RS + h * Dn + d;
    bf16x8 f;
#pragma unroll
    for (int j = 0; j < 8; ++j) f[j] = (__bf16)src[(size_t)j * RS];
    const int off = (d * 64 + koct * 16) ^ ((d & 3) << 4) ^ (((d >> 3) & 1) << 6);
    *(bf16x8*)((char*)VI + (size_t)chunk * 8192 + off) = f;
  }
}

// ============================================================================
// Main kernel: 512 blocks x 512 threads, 2/CU. Staging = 4 global_load_lds
// per wave per superstep (waves 0-3: K, waves 4-7: V) from the pre-swizzled
// images — zero staging VALU, zero ds_writes. K ring-4, V ring-4 (64 KB).
// Inner compute identical to verified R5.
// ============================================================================
__global__ __launch_bounds__(512)
void fa_fwd_dma(const float* __restrict__ Q, const __bf16* __restrict__ KI,
                const __bf16* __restrict__ VI, float* __restrict__ O)
{
  __shared__ __align__(16) __bf16 Klds[4][4096]; // 32 KB, ring by chunk &3
  __shared__ __align__(16) __bf16 Vt[4][4096];   // 32 KB, ring by chunk &3

  const int tid  = threadIdx.x;
  const int lane = tid & 63;
  const int wave = tid >> 6;
  const int col  = lane & 31;
  const int hi   = lane >> 5;
  const int grp  = wave >> 2;   // 0: even chunks, 1: odd chunks
  const int wq   = wave & 3;

  const int xcd  = (int)blockIdx.x & 7;
  const int s    = (int)blockIdx.x >> 3;    // 0..63
  const int hidx = xcd * 4 + (s & 3);       // 0..31
  const int b    = hidx >> 4, h = hidx & 15;
  const int s2   = s >> 2;                  // 0..15
  const int qt   = (s < 32) ? (15 - s2) : (s2 - 8);
  const int q0w  = qt * QBLK + wq * 32;
  const int T    = 2 * (qt + 1);            // supersteps
  const size_t base = ((size_t)b * Sn) * RS + (size_t)h * Dn;

  const char* KIc = (const char*)KI + (size_t)hidx * 64 * 8192;
  const char* VIc = (const char*)VI + (size_t)hidx * 64 * 8192;

  // staging roles: waves 0-3 stage K (2 chunks), 4-7 stage V (2 chunks).
  const int sr = wave >> 1;           // 0..3
  const int hb = (wave & 1) * 4096;   // byte half of an 8 KB chunk
  auto stageK2 = [&](int ss) {        // chunks 2ss, 2ss+1
    if (sr < 2) {
      const int ck = 2 * ss + sr;
      const char* g = KIc + (size_t)ck * 8192 + hb;
      char* l = (char*)&Klds[ck & 3][0] + hb;
#pragma unroll
      for (int i = 0; i < 4; ++i) cp16(g + i * 1024 + lane * 16, l + i * 1024);
    }
  };
  auto stageV2 = [&](int ss) {
    if (sr >= 2) {
      const int cv = 2 * ss + (sr - 2);
      const char* g = VIc + (size_t)cv * 8192 + hb;
      char* l = (char*)&Vt[cv & 3][0] + hb;
#pragma unroll
      for (int i = 0; i < 4; ++i) cp16(g + i * 1024 + lane * 16, l + i * 1024);
    }
  };

  const int cswz = (col & 7) << 4;
  const int vswz = ((col & 3) << 4) ^ (((col >> 3) & 1) << 6);

  // ---- Q fragments, scaled ----
  bf16x8 qf[8];
  {
    const float* qp = Q + base + (size_t)(q0w + col) * RS + hi * 8;
#pragma unroll
    for (int kk = 0; kk < 8; ++kk) {
      float4 a = *(const float4*)(qp + kk * 16);
      float4 c2 = *(const float4*)(qp + kk * 16 + 4);
      bf16x8 f;
      f[0] = (__bf16)(a.x * QSCALE);  f[1] = (__bf16)(a.y * QSCALE);
      f[2] = (__bf16)(a.z * QSCALE);  f[3] = (__bf16)(a.w * QSCALE);
      f[4] = (__bf16)(c2.x * QSCALE); f[5] = (__bf16)(c2.y * QSCALE);
      f[6] = (__bf16)(c2.z * QSCALE); f[7] = (__bf16)(c2.w * QSCALE);
      qf[kk] = f;
    }
  }

  f32x16 o0 = {}, o1 = {}, o2 = {}, o3 = {};
  float m = -1e30f, l = 0.f;

  // ---- prologue: DMA K(0),V(0),K(1); wait; S(0); fence ----
  stageK2(0);
  stageV2(0);
  stageK2(1);
  dma_barrier();                // K0,K1,V0 in LDS (vmcnt(0) covers Q loads too)

  f32x16 st_cur = {};
  if (grp * KVBLK <= q0w + 31) {
    const char* kb = (const char*)&Klds[grp][0];
    __builtin_amdgcn_s_setprio(1);
#pragma unroll
    for (int kk = 0; kk < 8; ++kk) {
      bf16x8 ka = *(const bf16x8*)(kb + ((col * 256 + kk * 32 + hi * 16) ^ cswz));
      st_cur = mfma32(ka, qf[kk], st_cur);
    }
    __builtin_amdgcn_s_setprio(0);
  }
  dma_barrier();                // fence S(0) slot-0/1 reads vs iter-0 K(2) DMA

#pragma unroll 1
  for (int t = 0; t < T; ++t) {
    // ---- issue next DMAs first: K(t+2) -> slots (2t)&3,(2t+1)&3 (reads
    // drained at iter t-1 barrier); V(t+1) -> slots (2t+2)&3,(2t+3)&3 ----
    if (t + 2 < T) stageK2(t + 2);
    if (t + 1 < T) stageV2(t + 1);

    // ---- QK^T(t+1) on the MFMA pipe ----
    f32x16 stn = {};
    const int icn = 2 * (t + 1) + grp;
    if (t + 1 < T && icn * KVBLK <= q0w + 31) {
      const char* kb = (const char*)&Klds[icn & 3][0];
      __builtin_amdgcn_s_setprio(1);
#pragma unroll
      for (int kk = 0; kk < 8; ++kk) {
        bf16x8 ka = *(const bf16x8*)(kb + ((col * 256 + kk * 32 + hi * 16) ^ cswz));
        stn = mfma32(ka, qf[kk], stn);
      }
      __builtin_amdgcn_s_setprio(0);
    }

    // ---- finish chunk t: mask, softmax, repack, PV ----
    const int kv0 = (2 * t + grp) * KVBLK;
    if (kv0 <= q0w + 31) {
      if (kv0 + KVBLK - 1 > q0w) {
        const int qk = q0w + col - kv0;
#pragma unroll
        for (int r = 0; r < 16; ++r) {
          const int krow = (r & 3) + 8 * (r >> 2) + 4 * hi;
          st_cur[r] = (krow <= qk) ? st_cur[r] : -1e30f;
        }
      }

      float t8[8];
#pragma unroll
      for (int r = 0; r < 8; ++r) t8[r] = fmaxf(st_cur[r], st_cur[r + 8]);
#pragma unroll
      for (int r = 0; r < 4; ++r) t8[r] = fmaxf(t8[r], t8[r + 4]);
      const float pmax = pair_max(fmaxf(fmaxf(t8[0], t8[1]), fmaxf(t8[2], t8[3])), hi);

      if (!__all(pmax <= m + 11.0f)) {   // T13 defer-max
        const float mnew = fmaxf(m, pmax);
        const float al = __builtin_amdgcn_exp2f(m - mnew);
        m = mnew;
        l *= al;
#pragma unroll
        for (int r = 0; r < 16; ++r) {
          const int row = (r & 3) + 8 * (r >> 2) + 4 * hi;
          const float ar = lane_bcast(row, al);
          o0[r] *= ar; o1[r] *= ar; o2[r] *= ar; o3[r] *= ar;
        }
      }

      float s4[4] = {0.f, 0.f, 0.f, 0.f};
#pragma unroll
      for (int r = 0; r < 16; ++r) {
        st_cur[r] = __builtin_amdgcn_exp2f(st_cur[r] - m);
        s4[r & 3] += st_cur[r];
      }
      l += pair_sum((s4[0] + s4[1]) + (s4[2] + s4[3]), hi);

      // P -> A-fragments via 4 permlane32_swap
      unsigned cw[8];
#pragma unroll
      for (int i = 0; i < 8; ++i) cw[i] = pack2(st_cur[2 * i], st_cur[2 * i + 1]);
      union { unsigned u[4]; bf16x8 v; } pa0, pa1;
      {
        auto s02 = __builtin_amdgcn_permlane32_swap(cw[0], cw[2], false, false);
        auto s13 = __builtin_amdgcn_permlane32_swap(cw[1], cw[3], false, false);
        auto s46 = __builtin_amdgcn_permlane32_swap(cw[4], cw[6], false, false);
        auto s57 = __builtin_amdgcn_permlane32_swap(cw[5], cw[7], false, false);
        pa0.u[0] = s02[0]; pa0.u[2] = s02[1];
        pa0.u[1] = s13[0]; pa0.u[3] = s13[1];
        pa1.u[0] = s46[0]; pa1.u[2] = s46[1];
        pa1.u[1] = s57[0]; pa1.u[3] = s57[1];
      }

      const char* vb = (const char*)&Vt[(2 * t + grp) & 3][0];
      __builtin_amdgcn_s_setprio(1);
#pragma unroll
      for (int ks = 0; ks < 2; ++ks) {
        const bf16x8 pa = ks ? pa1.v : pa0.v;
#define PV_STEP(ovar, dt) { \
        bf16x8 vf = *(const bf16x8*)(vb + ((((dt)*32 + col) * 64 + ks * 32 + hi * 16) ^ vswz)); \
        ovar = mfma32(pa, vf, ovar); }
        PV_STEP(o0, 0) PV_STEP(o1, 1) PV_STEP(o2, 2) PV_STEP(o3, 3)
#undef PV_STEP
      }
      __builtin_amdgcn_s_setprio(0);
    }
    dma_barrier();
    st_cur = stn;
  }

  // ---- merge group-1 partials into group-0 (LDS scratch over K/V rings) ----
  float* ob  = reinterpret_cast<float*>(&Klds[0][0]);   // 8192 floats (32 KB)
  float* mlb = reinterpret_cast<float*>(&Vt[0][0]);
  if (grp == 1) {
    mlb[wq * 128 + lane] = m;
    mlb[wq * 128 + 64 + lane] = l;
#pragma unroll
    for (int r = 0; r < 16; ++r) {
      ob[wq * 1024 + r * 64 + lane] = o0[r];
      ob[4096 + wq * 1024 + r * 64 + lane] = o1[r];
    }
  }
  __syncthreads();
  float f0 = 1.f, f1 = 0.f;
  if (grp == 0) {
    const float m1 = mlb[wq * 128 + lane];
    const float l1 = mlb[wq * 128 + 64 + lane];
    const float mS = fmaxf(m, m1);
    f0 = __builtin_amdgcn_exp2f(m - mS);
    f1 = __builtin_amdgcn_exp2f(m1 - mS);
    l = l * f0 + l1 * f1;
#pragma unroll
    for (int r = 0; r < 16; ++r) {
      const int row = (r & 3) + 8 * (r >> 2) + 4 * hi;
      const float a0 = lane_bcast(row, f0), a1 = lane_bcast(row, f1);
      o0[r] = o0[r] * a0 + ob[wq * 1024 + r * 64 + lane] * a1;
      o1[r] = o1[r] * a0 + ob[4096 + wq * 1024 + r * 64 + lane] * a1;
    }
  }
  __syncthreads();
  if (grp == 1) {
#pragma unroll
    for (int r = 0; r < 16; ++r) {
      ob[wq * 1024 + r * 64 + lane] = o2[r];
      ob[4096 + wq * 1024 + r * 64 + lane] = o3[r];
    }
  }
  __syncthreads();
  if (grp == 0) {
#pragma unroll
    for (int r = 0; r < 16; ++r) {
      const int row = (r & 3) + 8 * (r >> 2) + 4 * hi;
      const float a0 = lane_bcast(row, f0), a1 = lane_bcast(row, f1);
      o2[r] = o2[r] * a0 + ob[wq * 1024 + r * 64 + lane] * a1;
      o3[r] = o3[r] * a0 + ob[4096 + wq * 1024 + r * 64 + lane] * a1;
    }
    const float linv = 1.0f / l;
#pragma unroll
    for (int r = 0; r < 16; ++r) {
      const int row = (r & 3) + 8 * (r >> 2) + 4 * hi;
      const float lr = lane_bcast(row, linv);
      float* op = O + base + (size_t)(q0w + row) * RS + col;
      op[0]  = o0[r] * lr;
      op[32] = o1[r] * lr;
      op[64] = o2[r] * lr;
      op[96] = o3[r] * lr;
    }
  }
}

// ============================================================================
// Fallback: verbatim R5 kernel (104 µs) if workspace is too small.
// ============================================================================
__global__ __launch_bounds__(512)
void fa_fwd_reg(const float* __restrict__ Q, const float* __restrict__ K,
                const float* __restrict__ V, float* __restrict__ O)
{
  __shared__ __align__(16) __bf16 Klds[6][KVBLK * 128];
  __shared__ __align__(16) __bf16 Vt[4][128 * KVBLK];

  const int tid  = threadIdx.x;
  const int lane = tid & 63;
  const int wave = tid >> 6;
  const int col  = lane & 31;
  const int hi   = lane >> 5;
  const int grp  = wave >> 2;
  const int wq   = wave & 3;

  const int xcd  = (int)blockIdx.x & 7;
  const int s    = (int)blockIdx.x >> 3;
  const int hidx = xcd * 4 + (s & 3);
  const int b    = hidx >> 4, h = hidx & 15;
  const int s2   = s >> 2;
  const int qt   = (s < 32) ? (15 - s2) : (s2 - 8);
  const int q0w  = qt * QBLK + wq * 32;
  const int T    = 2 * (qt + 1);
  const size_t base = ((size_t)b * Sn) * RS + (size_t)h * Dn;

  const int sthalf = tid >> 8, ht = tid & 255;
  const int skey = ht >> 3, sd = (ht & 7) * 16;
  const int vkey4 = (ht & 7) * 4, vd4 = (ht >> 3) * 4;

  float4 kr[4], vr[4];
  auto loadK = [&](int ss) {
    const int kv0 = (2 * ss + sthalf) * KVBLK;
    const float* kp = K + base + (size_t)(kv0 + skey) * RS + sd;
#pragma unroll
    for (int i = 0; i < 4; ++i) kr[i] = *(const float4*)(kp + 4 * i);
  };
  auto loadV = [&](int ss) {
    const int kv0 = (2 * ss + sthalf) * KVBLK;
    const float* vp = V + base + (size_t)(kv0 + vkey4) * RS + vd4;
#pragma unroll
    for (int i = 0; i < 4; ++i) vr[i] = *(const float4*)(vp + (size_t)i * RS);
  };
  auto stageK = [&](int ss) {
    char* kb = (char*)&Klds[(2 * ss + sthalf) % 6][0];
    const int kbase = skey * 256 + sd * 2;
    const int kswz  = (skey & 7) << 4;
#pragma unroll
    for (int i = 0; i < 2; ++i) {
      bf16x8 f;
      f[0] = (__bf16)kr[2*i].x;   f[1] = (__bf16)kr[2*i].y;
      f[2] = (__bf16)kr[2*i].z;   f[3] = (__bf16)kr[2*i].w;
      f[4] = (__bf16)kr[2*i+1].x; f[5] = (__bf16)kr[2*i+1].y;
      f[6] = (__bf16)kr[2*i+1].z; f[7] = (__bf16)kr[2*i+1].w;
      *(bf16x8*)(kb + ((kbase + 16 * i) ^ kswz)) = f;
    }
  };
  auto stageV = [&](int ss) {
    char* vb = (char*)&Vt[(2 * ss + sthalf) & 3][0];
    const int b6 = ((vd4 >> 3) & 1) << 6;
#pragma unroll
    for (int j = 0; j < 4; ++j) {
      bf16x4 w;
      w[0] = (__bf16)f4e(vr[0], j);
      w[1] = (__bf16)f4e(vr[1], j);
      w[2] = (__bf16)f4e(vr[2], j);
      w[3] = (__bf16)f4e(vr[3], j);
      const int addr = (((vd4 + j) * 64 + vkey4 * 2) ^ (j << 4)) ^ b6;
      *(bf16x4*)(vb + addr) = w;
    }
  };

  const int cswz = (col & 7) << 4;
  const int vswz = ((col & 3) << 4) ^ (((col >> 3) & 1) << 6);

  bf16x8 qf[8];
  {
    const float* qp = Q + base + (size_t)(q0w + col) * RS + hi * 8;
#pragma unroll
    for (int kk = 0; kk < 8; ++kk) {
      float4 a = *(const float4*)(qp + kk * 16);
      float4 c2 = *(const float4*)(qp + kk * 16 + 4);
      bf16x8 f;
      f[0] = (__bf16)(a.x * QSCALE);  f[1] = (__bf16)(a.y * QSCALE);
      f[2] = (__bf16)(a.z * QSCALE);  f[3] = (__bf16)(a.w * QSCALE);
      f[4] = (__bf16)(c2.x * QSCALE); f[5] = (__bf16)(c2.y * QSCALE);
      f[6] = (__bf16)(c2.z * QSCALE); f[7] = (__bf16)(c2.w * QSCALE);
      qf[kk] = f;
    }
  }

  f32x16 o0 = {}, o1 = {}, o2 = {}, o3 = {};
  float m = -1e30f, l = 0.f;

  loadK(0); loadV(0);
  stageK(0);
  loadK(1);
  stageV(0);
  loadV(1);
  stageK(1);
  if (2 < T) loadK(2);
  pipeline_barrier();

  f32x16 st_cur = {};
  if (grp * KVBLK <= q0w + 31) {
    const char* kb = (const char*)&Klds[grp][0];
    __builtin_amdgcn_s_setprio(1);
#pragma unroll
    for (int kk = 0; kk < 8; ++kk) {
      bf16x8 ka = *(const bf16x8*)(kb + ((col * 256 + kk * 32 + hi * 16) ^ cswz));
      st_cur = mfma32(ka, qf[kk], st_cur);
    }
    __builtin_amdgcn_s_setprio(0);
  }

#pragma unroll 1
  for (int t = 0; t < T; ++t) {
    f32x16 stn = {};
    const int icn = 2 * (t + 1) + grp;
    if (t + 1 < T && icn * KVBLK <= q0w + 31) {
      const char* kb = (const char*)&Klds[icn % 6][0];
      __builtin_amdgcn_s_setprio(1);
#pragma unroll
      for (int kk = 0; kk < 8; ++kk) {
        bf16x8 ka = *(const bf16x8*)(kb + ((col * 256 + kk * 32 + hi * 16) ^ cswz));
        stn = mfma32(ka, qf[kk], stn);
      }
      __builtin_amdgcn_s_setprio(0);
    }

    if (t + 2 < T) stageK(t + 2);
    if (t + 1 < T) stageV(t + 1);
    if (t + 3 < T) loadK(t + 3);
    if (t + 2 < T) loadV(t + 2);

    const int kv0 = (2 * t + grp) * KVBLK;
    if (kv0 <= q0w + 31) {
      if (kv0 + KVBLK - 1 > q0w) {
        const int qk = q0w + col - kv0;
#pragma unroll
        for (int r = 0; r < 16; ++r) {
          const int krow = (r & 3) + 8 * (r >> 2) + 4 * hi;
          st_cur[r] = (krow <= qk) ? st_cur[r] : -1e30f;
        }
      }

      float t8[8];
#pragma unroll
      for (int r = 0; r < 8; ++r) t8[r] = fmaxf(st_cur[r], st_cur[r + 8]);
#pragma unroll
      for (int r = 0; r < 4; ++r) t8[r] = fmaxf(t8[r], t8[r + 4]);
      const float pmax = pair_max(fmaxf(fmaxf(t8[0], t8[1]), fmaxf(t8[2], t8[3])), hi);

      if (!__all(pmax <= m + 11.0f)) {
        const float mnew = fmaxf(m, pmax);
        const float al = __builtin_amdgcn_exp2f(m - mnew);
        m = mnew;
        l *= al;
#pragma unroll
        for (int r = 0; r < 16; ++r) {
          const int row = (r & 3) + 8 * (r >> 2) + 4 * hi;
          const float ar = lane_bcast(row, al);
          o0[r] *= ar; o1[r] *= ar; o2[r] *= ar; o3[r] *= ar;
        }
      }

      float s4[4] = {0.f, 0.f, 0.f, 0.f};
#pragma unroll
      for (int r = 0; r < 16; ++r) {
        st_cur[r] = __builtin_amdgcn_exp2f(st_cur[r] - m);
        s4[r & 3] += st_cur[r];
      }
      l += pair_sum((s4[0] + s4[1]) + (s4[2] + s4[3]), hi);

      unsigned cw[8];
#pragma unroll
      for (int i = 0; i < 8; ++i) cw[i] = pack2(st_cur[2 * i], st_cur[2 * i + 1]);
      union { unsigned u[4]; bf16x8 v; } pa0, pa1;
      {
        auto s02 = __builtin_amdgcn_permlane32_swap(cw[0], cw[2], false, false);
        auto s13 = __builtin_amdgcn_permlane32_swap(cw[1], cw[3], false, false);
        auto s46 = __builtin_amdgcn_permlane32_swap(cw[4], cw[6], false, false);
        auto s57 = __builtin_amdgcn_permlane32_swap(cw[5], cw[7], false, false);
        pa0.u[0] = s02[0]; pa0.u[2] = s02[1];
        pa0.u[1] = s13[0]; pa0.u[3] = s13[1];
        pa1.u[0] = s46[0]; pa1.u[2] = s46[1];
        pa1.u[1] = s57[0]; pa1.u[3] = s57[1];
      }

      const char* vb = (const char*)&Vt[(2 * t + grp) & 3][0];
      __builtin_amdgcn_s_setprio(1);
#pragma unroll
      for (int ks = 0; ks < 2; ++ks) {
        const bf16x8 pa = ks ? pa1.v : pa0.v;
#define PV_STEP(ovar, dt) { \
        bf16x8 vf = *(const bf16x8*)(vb + ((((dt)*32 + col) * 64 + ks * 32 + hi * 16) ^ vswz)); \
        ovar = mfma32(pa, vf, ovar); }
        PV_STEP(o0, 0) PV_STEP(o1, 1) PV_STEP(o2, 2) PV_STEP(o3, 3)
#undef PV_STEP
      }
      __builtin_amdgcn_s_setprio(0);
    }
    pipeline_barrier();
    st_cur = stn;
  }

  float* ob  = reinterpret_cast<float*>(&Klds[0][0]);
  float* mlb = reinterpret_cast<float*>(&Vt[0][0]);
  if (grp == 1) {
    mlb[wq * 128 + lane] = m;
    mlb[wq * 128 + 64 + lane] = l;
#pragma unroll
    for (int r = 0; r < 16; ++r) {
      ob[wq * 1024 + r * 64 + lane] = o0[r];
      ob[4096 + wq * 1024 + r * 64 + lane] = o1[r];
    }
  }
  __syncthreads();
  float f0 = 1.f, f1 = 0.f;
  if (grp == 0) {
    const float m1 = mlb[wq * 128 + lane];
    const float l1 = mlb[wq * 128 + 64 + lane];
    const float mS = fmaxf(m, m1);
    f0 = __builtin_amdgcn_exp2f(m - mS);
    f1 = __builtin_amdgcn_exp2f(m1 - mS);
    l = l * f0 + l1 * f1;
#pragma unroll
    for (int r = 0; r < 16; ++r) {
      const int row = (r & 3) + 8 * (r >> 2) + 4 * hi;
      const float a0 = lane_bcast(row, f0), a1 = lane_bcast(row, f1);
      o0[r] = o0[r] * a0 + ob[wq * 1024 + r * 64 + lane] * a1;
      o1[r] = o1[r] * a0 + ob[4096 + wq * 1024 + r * 64 + lane] * a1;
    }
  }
  __syncthreads();
  if (grp == 1) {
#pragma unroll
    for (int r = 0; r < 16; ++r) {
      ob[wq * 1024 + r * 64 + lane] = o2[r];
      ob[4096 + wq * 1024 + r * 64 + lane] = o3[r];
    }
  }
  __syncthreads();
  if (grp == 0) {
#pragma unroll
    for (int r = 0; r < 16; ++r) {
      const int row = (r & 3) + 8 * (r >> 2) + 4 * hi;
      const float a0 = lane_bcast(row, f0), a1 = lane_bcast(row, f1);
      o2[r] = o2[r] * a0 + ob[wq * 1024 + r * 64 + lane] * a1;
      o3[r] = o3[r] * a0 + ob[4096 + wq * 1024 + r * 64 + lane] * a1;
    }
    const float linv = 1.0f / l;
#pragma unroll
    for (int r = 0; r < 16; ++r) {
      const int row = (r & 3) + 8 * (r >> 2) + 4 * hi;
      const float lr = lane_bcast(row, linv);
      float* op = O + base + (size_t)(q0w + row) * RS + col;
      op[0]  = o0[r] * lr;
      op[32] = o1[r] * lr;
      op[64] = o2[r] * lr;
      op[96] = o3[r] * lr;
    }
  }
}

} // namespace

extern "C" void kernel_launch(void* const* d_in, const int* /*in_sizes*/, int /*n_in*/,
                              void* d_out, int /*out_size*/, void* d_ws, size_t ws_size,
                              hipStream_t stream) {
  const float* q = (const float*)d_in[0];
  const float* k = (const float*)d_in[1];
  const float* v = (const float*)d_in[2];
  float* o = (float*)d_out;
  if (d_ws != nullptr && ws_size >= WS_NEED) {
    __bf16* ki = (__bf16*)d_ws;
    __bf16* vi = (__bf16*)((char*)d_ws + IMG_BYTES);
    hipLaunchKernelGGL(prep_kv, dim3(8192), dim3(256), 0, stream, k, v, ki, vi);
    hipLaunchKernelGGL(fa_fwd_dma, dim3(512), dim3(512), 0, stream, q, ki, vi, o);
  } else {
    hipLaunchKernelGGL(fa_fwd_reg, dim3(512), dim3(512), 0, stream, q, k, v, o);
  }
}

// Round 7
// 97.296 us; speedup vs baseline: 5.3330x; 1.0519x over previous
//
#include <hip/hip_runtime.h>
#include <hip/hip_bf16.h>

namespace {

constexpr int Bn = 2, Sn = 2048, Hn = 16, Dn = 128;
constexpr int QBLK = 128;   // 4 q-waves x 32 queries, 2 key-groups
constexpr int KVBLK = 32;   // image chunk granularity (32 keys / 8 KB)
constexpr int RS = Hn * Dn; // 2048 floats
constexpr float QSCALE = 0.08838834764831845f * 1.4426950408889634f; // 1/sqrt(D)*log2(e)

// bf16 K/V images, pre-swizzled to the exact LDS chunk layout.
// 2048 chunks (2*16*64) x 8192 B each, K then V.
constexpr size_t IMG_BYTES = (size_t)Bn * Hn * 64 * 8192;   // 16 MB
constexpr size_t WS_NEED   = 2 * IMG_BYTES;                 // 32 MB

typedef __bf16 bf16x8 __attribute__((ext_vector_type(8)));
typedef __bf16 bf16x4 __attribute__((ext_vector_type(4)));
typedef float  f32x16 __attribute__((ext_vector_type(16)));

__device__ __forceinline__ f32x16 mfma32(bf16x8 a, bf16x8 b, f32x16 c) {
  return __builtin_amdgcn_mfma_f32_32x32x16_bf16(a, b, c, 0, 0, 0);
}
__device__ __forceinline__ unsigned pack2(float a, float b) {
  union { __bf16 h[2]; unsigned u; } r;
  r.h[0] = (__bf16)a; r.h[1] = (__bf16)b;
  return r.u;
}
// lane<->lane^32 exchange on the VALU pipe (T12 primitive).
__device__ __forceinline__ float pair_max(float x, int hi) {
  auto r = __builtin_amdgcn_permlane32_swap(__float_as_uint(x), __float_as_uint(x), false, false);
  const float sw = __uint_as_float(hi ? r[0] : r[1]);
  return fmaxf(x, sw);
}
__device__ __forceinline__ float pair_sum(float x, int hi) {
  auto r = __builtin_amdgcn_permlane32_swap(__float_as_uint(x), __float_as_uint(x), false, false);
  const float sw = __uint_as_float(hi ? r[0] : r[1]);
  return x + sw;
}
__device__ __forceinline__ float f4e(const float4& v, int j) {
  return j == 0 ? v.x : j == 1 ? v.y : j == 2 ? v.z : v.w;
}
__device__ __forceinline__ float lane_bcast(int row, float v) {
  return __uint_as_float(__builtin_amdgcn_ds_bpermute(row * 4, __float_as_uint(v)));
}

// async 16B global->LDS DMA (linear dest: uniform lds base + lane*16)
__device__ __forceinline__ void cp16(const char* g, char* l) {
  __builtin_amdgcn_global_load_lds(
      (const __attribute__((address_space(1))) void*)g,
      (__attribute__((address_space(3))) void*)l, 16, 0, 0);
}

// full barrier: DMA'd LDS + ds ops visible to all waves.
__device__ __forceinline__ void dma_barrier() {
  __builtin_amdgcn_sched_barrier(0);
  asm volatile("s_waitcnt vmcnt(0) lgkmcnt(0)" ::: "memory");
  __builtin_amdgcn_s_barrier();
  __builtin_amdgcn_sched_barrier(0);
}
// lgkm-only barrier (fallback kernel): leaves reg-destined prefetches in flight.
__device__ __forceinline__ void pipeline_barrier() {
  __builtin_amdgcn_sched_barrier(0);
  asm volatile("s_waitcnt lgkmcnt(0)" ::: "memory");
  __builtin_amdgcn_s_barrier();
  __builtin_amdgcn_sched_barrier(0);
}

// ============================================================================
// Pre-pass: fp32 K/V -> bf16 images in the EXACT swizzled LDS chunk layout.
// (verbatim from R6, verified)
// ============================================================================
__global__ __launch_bounds__(256)
void prep_kv(const float* __restrict__ K, const float* __restrict__ V,
             __bf16* __restrict__ KI, __bf16* __restrict__ VI)
{
  const int gid  = (int)blockIdx.x * 256 + (int)threadIdx.x; // 0..2M
  const int half = gid >> 20;              // 0=K, 1=V
  const int id   = gid & ((1 << 20) - 1);  // 0..1M
  const int chunk = id >> 9;               // 0..2047
  const int rem   = id & 511;
  const int bh = chunk >> 6, c = chunk & 63;
  const int b = bh >> 4, h = bh & 15;
  if (half == 0) {
    const int key = rem >> 4, dblk = rem & 15;
    const float* src = K + ((size_t)b * Sn + (size_t)c * 32 + key) * RS + h * Dn + dblk * 8;
    float4 a  = *(const float4*)src;
    float4 c2 = *(const float4*)(src + 4);
    bf16x8 f;
    f[0] = (__bf16)a.x;  f[1] = (__bf16)a.y;  f[2] = (__bf16)a.z;  f[3] = (__bf16)a.w;
    f[4] = (__bf16)c2.x; f[5] = (__bf16)c2.y; f[6] = (__bf16)c2.z; f[7] = (__bf16)c2.w;
    char* dst = (char*)KI + (size_t)chunk * 8192 + ((key * 256 + dblk * 16) ^ ((key & 7) << 4));
    *(bf16x8*)dst = f;
  } else {
    const int d = rem >> 2, koct = rem & 3;
    const float* src = V + ((size_t)b * Sn + (size_t)c * 32 + koct * 8) * RS + h * Dn + d;
    bf16x8 f;
#pragma unroll
    for (int j = 0; j < 8; ++j) f[j] = (__bf16)src[(size_t)j * RS];
    const int off = (d * 64 + koct * 16) ^ ((d & 3) << 4) ^ (((d >> 3) & 1) << 6);
    *(bf16x8*)((char*)VI + (size_t)chunk * 8192 + off) = f;
  }
}

// ============================================================================
// Main kernel: 256 blocks (1/CU, 128 KB LDS) x 512 threads.
// Superstep = 128 keys (4 chunk32s): group 0 -> subs 4t,4t+1; group 1 ->
// 4t+2,4t+3. Block p runs tiles (15-p) then (p) SEQUENTIALLY: every CU =
// (16-p)+(p+1) = 17 double-supersteps -> perfectly uniform makespan.
// K ring-8, V ring-8 by chunk32&7; DMA staged one barrier ahead (K two
// supersteps of chunks live; V one + in-flight). Inner compute = verified
// R6 code per 32-key sub-chunk with wave-uniform validity guards.
// ============================================================================
__global__ __launch_bounds__(512)
void fa_fwd_dma(const float* __restrict__ Q, const __bf16* __restrict__ KI,
                const __bf16* __restrict__ VI, float* __restrict__ O)
{
  __shared__ __align__(16) __bf16 Klds[8][4096]; // 64 KB, slot = chunk32 & 7
  __shared__ __align__(16) __bf16 Vt[8][4096];   // 64 KB, slot = chunk32 & 7

  const int tid  = threadIdx.x;
  const int lane = tid & 63;
  const int wave = tid >> 6;
  const int col  = lane & 31;
  const int hi   = lane >> 5;
  const int grp  = wave >> 2;   // key-group: subs 4t+2grp, 4t+2grp+1
  const int wq   = wave & 3;

  const int xcd  = (int)blockIdx.x & 7;
  const int s    = (int)blockIdx.x >> 3;    // 0..31
  const int hidx = xcd * 4 + (s & 3);       // 0..31
  const int b    = hidx >> 4, h = hidx & 15;
  const int p    = s >> 2;                  // pair 0..7
  const size_t base = ((size_t)b * Sn) * RS + (size_t)h * Dn;

  const char* KIc = (const char*)KI + (size_t)hidx * 64 * 8192;
  const char* VIc = (const char*)VI + (size_t)hidx * 64 * 8192;

  // per-wave DMA of one 8 KB chunk32 (8x 1 KB rows)
  auto stageKc = [&](int cc) {
    const char* g = KIc + (size_t)cc * 8192 + lane * 16;
    char* l = (char*)&Klds[cc & 7][0];
#pragma unroll
    for (int i = 0; i < 8; ++i) cp16(g + i * 1024, l + i * 1024);
  };
  auto stageVc = [&](int cc) {
    const char* g = VIc + (size_t)cc * 8192 + lane * 16;
    char* l = (char*)&Vt[cc & 7][0];
#pragma unroll
    for (int i = 0; i < 8; ++i) cp16(g + i * 1024, l + i * 1024);
  };

  const int cswz = (col & 7) << 4;
  const int vswz = ((col & 3) << 4) ^ (((col >> 3) & 1) << 6);

#define QK8(kbp, acc) { \
  __builtin_amdgcn_s_setprio(1); \
  _Pragma("unroll") \
  for (int kk = 0; kk < 8; ++kk) { \
    bf16x8 ka = *(const bf16x8*)((kbp) + ((col * 256 + kk * 32 + hi * 16) ^ cswz)); \
    acc = mfma32(ka, qf[kk], acc); \
  } \
  __builtin_amdgcn_s_setprio(0); }

#pragma unroll 1
  for (int tp = 0; tp < 2; ++tp) {
    const int qt  = tp ? p : (15 - p);
    const int q0w = qt * QBLK + wq * 32;
    const int T   = qt + 1;              // supersteps of 128 keys

    // ---- Q fragments, scaled ----
    bf16x8 qf[8];
    {
      const float* qp = Q + base + (size_t)(q0w + col) * RS + hi * 8;
#pragma unroll
      for (int kk = 0; kk < 8; ++kk) {
        float4 a = *(const float4*)(qp + kk * 16);
        float4 c2 = *(const float4*)(qp + kk * 16 + 4);
        bf16x8 f;
        f[0] = (__bf16)(a.x * QSCALE);  f[1] = (__bf16)(a.y * QSCALE);
        f[2] = (__bf16)(a.z * QSCALE);  f[3] = (__bf16)(a.w * QSCALE);
        f[4] = (__bf16)(c2.x * QSCALE); f[5] = (__bf16)(c2.y * QSCALE);
        f[6] = (__bf16)(c2.z * QSCALE); f[7] = (__bf16)(c2.w * QSCALE);
        qf[kk] = f;
      }
    }

    f32x16 o0 = {}, o1 = {}, o2 = {}, o3 = {};
    float m = -1e30f, l = 0.f;

    // ---- prologue: superstep-0 K(0..3)+V(0..3); K(4..7) if T>1 ----
    if (wave < 4) stageKc(wave); else stageVc(wave - 4);
    if (T > 1 && wave < 4) stageKc(4 + wave);
    dma_barrier();

    // S(0): subs cc = 2grp, 2grp+1
    f32x16 sc0 = {}, sc1 = {};
    {
      const int cc = 2 * grp;
      if (cc * 32 <= q0w + 31) {
        const char* kb = (const char*)&Klds[cc][0];
        QK8(kb, sc0)
        if ((cc + 1) * 32 <= q0w + 31) {
          const char* kb1 = (const char*)&Klds[cc + 1][0];
          QK8(kb1, sc1)
        }
      }
    }
    dma_barrier();   // fence S(0) slot 0..3 reads vs iter-0 K DMA (slots 0..3)

#pragma unroll 1
    for (int t = 0; t < T; ++t) {
      // ---- issue next DMAs: K(t+2) -> slots (4t+j)&7 (reads drained at
      // barrier t-1); V(t+1) -> slots (4t+4+j)&7 (disjoint from PV(t)) ----
      if (t + 2 < T && wave < 4) stageKc(4 * (t + 2) + wave);
      if (t + 1 < T && wave >= 4) stageVc(4 * (t + 1) + (wave - 4));

      // ---- QK^T(t+1) on the MFMA pipe ----
      f32x16 sn0 = {}, sn1 = {};
      if (t + 1 < T) {
        const int cc = 4 * (t + 1) + 2 * grp;
        if (cc * 32 <= q0w + 31) {
          const char* kb = (const char*)&Klds[cc & 7][0];
          QK8(kb, sn0)
          if ((cc + 1) * 32 <= q0w + 31) {
            const char* kb1 = (const char*)&Klds[(cc + 1) & 7][0];
            QK8(kb1, sn1)
          }
        }
      }

      // ---- finish superstep t: mask, softmax, repack, PV (2 subs) ----
      const int cc0 = 4 * t + 2 * grp;
      const int kv0 = cc0 * 32;
      if (kv0 <= q0w + 31) {
        const bool v1 = (kv0 + 32) <= q0w + 31;   // wave-uniform

        if (kv0 + 31 > q0w) {
          const int qk = q0w + col - kv0;
#pragma unroll
          for (int r = 0; r < 16; ++r) {
            const int krow = (r & 3) + 8 * (r >> 2) + 4 * hi;
            sc0[r] = (krow <= qk) ? sc0[r] : -1e30f;
          }
        }
        if (v1 && kv0 + 63 > q0w) {
          const int qk1 = q0w + col - (kv0 + 32);
#pragma unroll
          for (int r = 0; r < 16; ++r) {
            const int krow = (r & 3) + 8 * (r >> 2) + 4 * hi;
            sc1[r] = (krow <= qk1) ? sc1[r] : -1e30f;
          }
        }

        float t8[8];
#pragma unroll
        for (int r = 0; r < 8; ++r) t8[r] = fmaxf(sc0[r], sc0[r + 8]);
        if (v1) {
#pragma unroll
          for (int r = 0; r < 8; ++r) t8[r] = fmaxf(t8[r], fmaxf(sc1[r], sc1[r + 8]));
        }
#pragma unroll
        for (int r = 0; r < 4; ++r) t8[r] = fmaxf(t8[r], t8[r + 4]);
        const float pmax = pair_max(fmaxf(fmaxf(t8[0], t8[1]), fmaxf(t8[2], t8[3])), hi);

        if (!__all(pmax <= m + 11.0f)) {   // T13 defer-max
          const float mnew = fmaxf(m, pmax);
          const float al = __builtin_amdgcn_exp2f(m - mnew);
          m = mnew;
          l *= al;
#pragma unroll
          for (int r = 0; r < 16; ++r) {
            const int row = (r & 3) + 8 * (r >> 2) + 4 * hi;
            const float ar = lane_bcast(row, al);
            o0[r] *= ar; o1[r] *= ar; o2[r] *= ar; o3[r] *= ar;
          }
        }

        float s4[4] = {0.f, 0.f, 0.f, 0.f};
#pragma unroll
        for (int r = 0; r < 16; ++r) {
          sc0[r] = __builtin_amdgcn_exp2f(sc0[r] - m);
          s4[r & 3] += sc0[r];
        }
        if (v1) {
#pragma unroll
          for (int r = 0; r < 16; ++r) {
            sc1[r] = __builtin_amdgcn_exp2f(sc1[r] - m);
            s4[r & 3] += sc1[r];
          }
        }
        l += pair_sum((s4[0] + s4[1]) + (s4[2] + s4[3]), hi);

        // P -> A-fragments via permlane32_swap (per sub)
        union { unsigned u[4]; bf16x8 v; } pa0, pa1, pb0, pb1;
        {
          unsigned cw[8];
#pragma unroll
          for (int i = 0; i < 8; ++i) cw[i] = pack2(sc0[2 * i], sc0[2 * i + 1]);
          auto s02 = __builtin_amdgcn_permlane32_swap(cw[0], cw[2], false, false);
          auto s13 = __builtin_amdgcn_permlane32_swap(cw[1], cw[3], false, false);
          auto s46 = __builtin_amdgcn_permlane32_swap(cw[4], cw[6], false, false);
          auto s57 = __builtin_amdgcn_permlane32_swap(cw[5], cw[7], false, false);
          pa0.u[0] = s02[0]; pa0.u[2] = s02[1];
          pa0.u[1] = s13[0]; pa0.u[3] = s13[1];
          pa1.u[0] = s46[0]; pa1.u[2] = s46[1];
          pa1.u[1] = s57[0]; pa1.u[3] = s57[1];
        }
        if (v1) {
          unsigned cw[8];
#pragma unroll
          for (int i = 0; i < 8; ++i) cw[i] = pack2(sc1[2 * i], sc1[2 * i + 1]);
          auto s02 = __builtin_amdgcn_permlane32_swap(cw[0], cw[2], false, false);
          auto s13 = __builtin_amdgcn_permlane32_swap(cw[1], cw[3], false, false);
          auto s46 = __builtin_amdgcn_permlane32_swap(cw[4], cw[6], false, false);
          auto s57 = __builtin_amdgcn_permlane32_swap(cw[5], cw[7], false, false);
          pb0.u[0] = s02[0]; pb0.u[2] = s02[1];
          pb0.u[1] = s13[0]; pb0.u[3] = s13[1];
          pb1.u[0] = s46[0]; pb1.u[2] = s46[1];
          pb1.u[1] = s57[0]; pb1.u[3] = s57[1];
        }

        const char* vb0 = (const char*)&Vt[cc0 & 7][0];
        const char* vb1 = (const char*)&Vt[(cc0 + 1) & 7][0];
        __builtin_amdgcn_s_setprio(1);
#pragma unroll
        for (int ks = 0; ks < 2; ++ks) {
          const bf16x8 pa = ks ? pa1.v : pa0.v;
#define PV_STEP(ovar, dt, vbp) { \
          bf16x8 vf = *(const bf16x8*)((vbp) + ((((dt)*32 + col) * 64 + ks * 32 + hi * 16) ^ vswz)); \
          ovar = mfma32(pa, vf, ovar); }
          PV_STEP(o0, 0, vb0) PV_STEP(o1, 1, vb0) PV_STEP(o2, 2, vb0) PV_STEP(o3, 3, vb0)
        }
        if (v1) {
#pragma unroll
          for (int ks = 0; ks < 2; ++ks) {
            const bf16x8 pa = ks ? pb1.v : pb0.v;
            PV_STEP(o0, 0, vb1) PV_STEP(o1, 1, vb1) PV_STEP(o2, 2, vb1) PV_STEP(o3, 3, vb1)
#undef PV_STEP
          }
        }
        __builtin_amdgcn_s_setprio(0);
      }
      dma_barrier();
      sc0 = sn0; sc1 = sn1;
    }

    // ---- merge group-1 partials into group-0 (LDS scratch over rings) ----
    float* ob  = reinterpret_cast<float*>(&Klds[0][0]);   // 8192 floats (32 KB)
    float* mlb = reinterpret_cast<float*>(&Vt[0][0]);
    if (grp == 1) {
      mlb[wq * 128 + lane] = m;
      mlb[wq * 128 + 64 + lane] = l;
#pragma unroll
      for (int r = 0; r < 16; ++r) {
        ob[wq * 1024 + r * 64 + lane] = o0[r];
        ob[4096 + wq * 1024 + r * 64 + lane] = o1[r];
      }
    }
    __syncthreads();
    float f0 = 1.f, f1 = 0.f;
    if (grp == 0) {
      const float m1 = mlb[wq * 128 + lane];
      const float l1 = mlb[wq * 128 + 64 + lane];
      const float mS = fmaxf(m, m1);
      f0 = __builtin_amdgcn_exp2f(m - mS);
      f1 = __builtin_amdgcn_exp2f(m1 - mS);
      l = l * f0 + l1 * f1;
#pragma unroll
      for (int r = 0; r < 16; ++r) {
        const int row = (r & 3) + 8 * (r >> 2) + 4 * hi;
        const float a0 = lane_bcast(row, f0), a1 = lane_bcast(row, f1);
        o0[r] = o0[r] * a0 + ob[wq * 1024 + r * 64 + lane] * a1;
        o1[r] = o1[r] * a0 + ob[4096 + wq * 1024 + r * 64 + lane] * a1;
      }
    }
    __syncthreads();
    if (grp == 1) {
#pragma unroll
      for (int r = 0; r < 16; ++r) {
        ob[wq * 1024 + r * 64 + lane] = o2[r];
        ob[4096 + wq * 1024 + r * 64 + lane] = o3[r];
      }
    }
    __syncthreads();
    if (grp == 0) {
#pragma unroll
      for (int r = 0; r < 16; ++r) {
        const int row = (r & 3) + 8 * (r >> 2) + 4 * hi;
        const float a0 = lane_bcast(row, f0), a1 = lane_bcast(row, f1);
        o2[r] = o2[r] * a0 + ob[wq * 1024 + r * 64 + lane] * a1;
        o3[r] = o3[r] * a0 + ob[4096 + wq * 1024 + r * 64 + lane] * a1;
      }
      const float linv = 1.0f / l;
#pragma unroll
      for (int r = 0; r < 16; ++r) {
        const int row = (r & 3) + 8 * (r >> 2) + 4 * hi;
        const float lr = lane_bcast(row, linv);
        float* op = O + base + (size_t)(q0w + row) * RS + col;
        op[0]  = o0[r] * lr;
        op[32] = o1[r] * lr;
        op[64] = o2[r] * lr;
        op[96] = o3[r] * lr;
      }
    }
    __syncthreads();   // protect merge scratch before next tile's staging
  }
#undef QK8
}

// ============================================================================
// Fallback: verbatim R5 kernel (104 µs) if workspace is too small.
// ============================================================================
__global__ __launch_bounds__(512)
void fa_fwd_reg(const float* __restrict__ Q, const float* __restrict__ K,
                const float* __restrict__ V, float* __restrict__ O)
{
  __shared__ __align__(16) __bf16 Klds[6][KVBLK * 128];
  __shared__ __align__(16) __bf16 Vt[4][128 * KVBLK];

  const int tid  = threadIdx.x;
  const int lane = tid & 63;
  const int wave = tid >> 6;
  const int col  = lane & 31;
  const int hi   = lane >> 5;
  const int grp  = wave >> 2;
  const int wq   = wave & 3;

  const int xcd  = (int)blockIdx.x & 7;
  const int s    = (int)blockIdx.x >> 3;
  const int hidx = xcd * 4 + (s & 3);
  const int b    = hidx >> 4, h = hidx & 15;
  const int s2   = s >> 2;
  const int qt   = (s < 32) ? (15 - s2) : (s2 - 8);
  const int q0w  = qt * QBLK + wq * 32;
  const int T    = 2 * (qt + 1);
  const size_t base = ((size_t)b * Sn) * RS + (size_t)h * Dn;

  const int sthalf = tid >> 8, ht = tid & 255;
  const int skey = ht >> 3, sd = (ht & 7) * 16;
  const int vkey4 = (ht & 7) * 4, vd4 = (ht >> 3) * 4;

  float4 kr[4], vr[4];
  auto loadK = [&](int ss) {
    const int kv0 = (2 * ss + sthalf) * KVBLK;
    const float* kp = K + base + (size_t)(kv0 + skey) * RS + sd;
#pragma unroll
    for (int i = 0; i < 4; ++i) kr[i] = *(const float4*)(kp + 4 * i);
  };
  auto loadV = [&](int ss) {
    const int kv0 = (2 * ss + sthalf) * KVBLK;
    const float* vp = V + base + (size_t)(kv0 + vkey4) * RS + vd4;
#pragma unroll
    for (int i = 0; i < 4; ++i) vr[i] = *(const float4*)(vp + (size_t)i * RS);
  };
  auto stageK = [&](int ss) {
    char* kb = (char*)&Klds[(2 * ss + sthalf) % 6][0];
    const int kbase = skey * 256 + sd * 2;
    const int kswz  = (skey & 7) << 4;
#pragma unroll
    for (int i = 0; i < 2; ++i) {
      bf16x8 f;
      f[0] = (__bf16)kr[2*i].x;   f[1] = (__bf16)kr[2*i].y;
      f[2] = (__bf16)kr[2*i].z;   f[3] = (__bf16)kr[2*i].w;
      f[4] = (__bf16)kr[2*i+1].x; f[5] = (__bf16)kr[2*i+1].y;
      f[6] = (__bf16)kr[2*i+1].z; f[7] = (__bf16)kr[2*i+1].w;
      *(bf16x8*)(kb + ((kbase + 16 * i) ^ kswz)) = f;
    }
  };
  auto stageV = [&](int ss) {
    char* vb = (char*)&Vt[(2 * ss + sthalf) & 3][0];
    const int b6 = ((vd4 >> 3) & 1) << 6;
#pragma unroll
    for (int j = 0; j < 4; ++j) {
      bf16x4 w;
      w[0] = (__bf16)f4e(vr[0], j);
      w[1] = (__bf16)f4e(vr[1], j);
      w[2] = (__bf16)f4e(vr[2], j);
      w[3] = (__bf16)f4e(vr[3], j);
      const int addr = (((vd4 + j) * 64 + vkey4 * 2) ^ (j << 4)) ^ b6;
      *(bf16x4*)(vb + addr) = w;
    }
  };

  const int cswz = (col & 7) << 4;
  const int vswz = ((col & 3) << 4) ^ (((col >> 3) & 1) << 6);

  bf16x8 qf[8];
  {
    const float* qp = Q + base + (size_t)(q0w + col) * RS + hi * 8;
#pragma unroll
    for (int kk = 0; kk < 8; ++kk) {
      float4 a = *(const float4*)(qp + kk * 16);
      float4 c2 = *(const float4*)(qp + kk * 16 + 4);
      bf16x8 f;
      f[0] = (__bf16)(a.x * QSCALE);  f[1] = (__bf16)(a.y * QSCALE);
      f[2] = (__bf16)(a.z * QSCALE);  f[3] = (__bf16)(a.w * QSCALE);
      f[4] = (__bf16)(c2.x * QSCALE); f[5] = (__bf16)(c2.y * QSCALE);
      f[6] = (__bf16)(c2.z * QSCALE); f[7] = (__bf16)(c2.w * QSCALE);
      qf[kk] = f;
    }
  }

  f32x16 o0 = {}, o1 = {}, o2 = {}, o3 = {};
  float m = -1e30f, l = 0.f;

  loadK(0); loadV(0);
  stageK(0);
  loadK(1);
  stageV(0);
  loadV(1);
  stageK(1);
  if (2 < T) loadK(2);
  pipeline_barrier();

  f32x16 st_cur = {};
  if (grp * KVBLK <= q0w + 31) {
    const char* kb = (const char*)&Klds[grp][0];
    __builtin_amdgcn_s_setprio(1);
#pragma unroll
    for (int kk = 0; kk < 8; ++kk) {
      bf16x8 ka = *(const bf16x8*)(kb + ((col * 256 + kk * 32 + hi * 16) ^ cswz));
      st_cur = mfma32(ka, qf[kk], st_cur);
    }
    __builtin_amdgcn_s_setprio(0);
  }

#pragma unroll 1
  for (int t = 0; t < T; ++t) {
    f32x16 stn = {};
    const int icn = 2 * (t + 1) + grp;
    if (t + 1 < T && icn * KVBLK <= q0w + 31) {
      const char* kb = (const char*)&Klds[icn % 6][0];
      __builtin_amdgcn_s_setprio(1);
#pragma unroll
      for (int kk = 0; kk < 8; ++kk) {
        bf16x8 ka = *(const bf16x8*)(kb + ((col * 256 + kk * 32 + hi * 16) ^ cswz));
        stn = mfma32(ka, qf[kk], stn);
      }
      __builtin_amdgcn_s_setprio(0);
    }

    if (t + 2 < T) stageK(t + 2);
    if (t + 1 < T) stageV(t + 1);
    if (t + 3 < T) loadK(t + 3);
    if (t + 2 < T) loadV(t + 2);

    const int kv0 = (2 * t + grp) * KVBLK;
    if (kv0 <= q0w + 31) {
      if (kv0 + KVBLK - 1 > q0w) {
        const int qk = q0w + col - kv0;
#pragma unroll
        for (int r = 0; r < 16; ++r) {
          const int krow = (r & 3) + 8 * (r >> 2) + 4 * hi;
          st_cur[r] = (krow <= qk) ? st_cur[r] : -1e30f;
        }
      }

      float t8[8];
#pragma unroll
      for (int r = 0; r < 8; ++r) t8[r] = fmaxf(st_cur[r], st_cur[r + 8]);
#pragma unroll
      for (int r = 0; r < 4; ++r) t8[r] = fmaxf(t8[r], t8[r + 4]);
      const float pmax = pair_max(fmaxf(fmaxf(t8[0], t8[1]), fmaxf(t8[2], t8[3])), hi);

      if (!__all(pmax <= m + 11.0f)) {
        const float mnew = fmaxf(m, pmax);
        const float al = __builtin_amdgcn_exp2f(m - mnew);
        m = mnew;
        l *= al;
#pragma unroll
        for (int r = 0; r < 16; ++r) {
          const int row = (r & 3) + 8 * (r >> 2) + 4 * hi;
          const float ar = lane_bcast(row, al);
          o0[r] *= ar; o1[r] *= ar; o2[r] *= ar; o3[r] *= ar;
        }
      }

      float s4[4] = {0.f, 0.f, 0.f, 0.f};
#pragma unroll
      for (int r = 0; r < 16; ++r) {
        st_cur[r] = __builtin_amdgcn_exp2f(st_cur[r] - m);
        s4[r & 3] += st_cur[r];
      }
      l += pair_sum((s4[0] + s4[1]) + (s4[2] + s4[3]), hi);

      unsigned cw[8];
#pragma unroll
      for (int i = 0; i < 8; ++i) cw[i] = pack2(st_cur[2 * i], st_cur[2 * i + 1]);
      union { unsigned u[4]; bf16x8 v; } pa0, pa1;
      {
        auto s02 = __builtin_amdgcn_permlane32_swap(cw[0], cw[2], false, false);
        auto s13 = __builtin_amdgcn_permlane32_swap(cw[1], cw[3], false, false);
        auto s46 = __builtin_amdgcn_permlane32_swap(cw[4], cw[6], false, false);
        auto s57 = __builtin_amdgcn_permlane32_swap(cw[5], cw[7], false, false);
        pa0.u[0] = s02[0]; pa0.u[2] = s02[1];
        pa0.u[1] = s13[0]; pa0.u[3] = s13[1];
        pa1.u[0] = s46[0]; pa1.u[2] = s46[1];
        pa1.u[1] = s57[0]; pa1.u[3] = s57[1];
      }

      const char* vb = (const char*)&Vt[(2 * t + grp) & 3][0];
      __builtin_amdgcn_s_setprio(1);
#pragma unroll
      for (int ks = 0; ks < 2; ++ks) {
        const bf16x8 pa = ks ? pa1.v : pa0.v;
#define PV_STEP(ovar, dt) { \
        bf16x8 vf = *(const bf16x8*)(vb + ((((dt)*32 + col) * 64 + ks * 32 + hi * 16) ^ vswz)); \
        ovar = mfma32(pa, vf, ovar); }
        PV_STEP(o0, 0) PV_STEP(o1, 1) PV_STEP(o2, 2) PV_STEP(o3, 3)
#undef PV_STEP
      }
      __builtin_amdgcn_s_setprio(0);
    }
    pipeline_barrier();
    st_cur = stn;
  }

  float* ob  = reinterpret_cast<float*>(&Klds[0][0]);
  float* mlb = reinterpret_cast<float*>(&Vt[0][0]);
  if (grp == 1) {
    mlb[wq * 128 + lane] = m;
    mlb[wq * 128 + 64 + lane] = l;
#pragma unroll
    for (int r = 0; r < 16; ++r) {
      ob[wq * 1024 + r * 64 + lane] = o0[r];
      ob[4096 + wq * 1024 + r * 64 + lane] = o1[r];
    }
  }
  __syncthreads();
  float f0 = 1.f, f1 = 0.f;
  if (grp == 0) {
    const float m1 = mlb[wq * 128 + lane];
    const float l1 = mlb[wq * 128 + 64 + lane];
    const float mS = fmaxf(m, m1);
    f0 = __builtin_amdgcn_exp2f(m - mS);
    f1 = __builtin_amdgcn_exp2f(m1 - mS);
    l = l * f0 + l1 * f1;
#pragma unroll
    for (int r = 0; r < 16; ++r) {
      const int row = (r & 3) + 8 * (r >> 2) + 4 * hi;
      const float a0 = lane_bcast(row, f0), a1 = lane_bcast(row, f1);
      o0[r] = o0[r] * a0 + ob[wq * 1024 + r * 64 + lane] * a1;
      o1[r] = o1[r] * a0 + ob[4096 + wq * 1024 + r * 64 + lane] * a1;
    }
  }
  __syncthreads();
  if (grp == 1) {
#pragma unroll
    for (int r = 0; r < 16; ++r) {
      ob[wq * 1024 + r * 64 + lane] = o2[r];
      ob[4096 + wq * 1024 + r * 64 + lane] = o3[r];
    }
  }
  __syncthreads();
  if (grp == 0) {
#pragma unroll
    for (int r = 0; r < 16; ++r) {
      const int row = (r & 3) + 8 * (r >> 2) + 4 * hi;
      const float a0 = lane_bcast(row, f0), a1 = lane_bcast(row, f1);
      o2[r] = o2[r] * a0 + ob[wq * 1024 + r * 64 + lane] * a1;
      o3[r] = o3[r] * a0 + ob[4096 + wq * 1024 + r * 64 + lane] * a1;
    }
    const float linv = 1.0f / l;
#pragma unroll
    for (int r = 0; r < 16; ++r) {
      const int row = (r & 3) + 8 * (r >> 2) + 4 * hi;
      const float lr = lane_bcast(row, linv);
      float* op = O + base + (size_t)(q0w + row) * RS + col;
      op[0]  = o0[r] * lr;
      op[32] = o1[r] * lr;
      op[64] = o2[r] * lr;
      op[96] = o3[r] * lr;
    }
  }
}

} // namespace

extern "C" void kernel_launch(void* const* d_in, const int* /*in_sizes*/, int /*n_in*/,
                              void* d_out, int /*out_size*/, void* d_ws, size_t ws_size,
                              hipStream_t stream) {
  const float* q = (const float*)d_in[0];
  const float* k = (const float*)d_in[1];
  const float* v = (const float*)d_in[2];
  float* o = (float*)d_out;
  if (d_ws != nullptr && ws_size >= WS_NEED) {
    __bf16* ki = (__bf16*)d_ws;
    __bf16* vi = (__bf16*)((char*)d_ws + IMG_BYTES);
    hipLaunchKernelGGL(prep_kv, dim3(8192), dim3(256), 0, stream, k, v, ki, vi);
    hipLaunchKernelGGL(fa_fwd_dma, dim3(256), dim3(512), 0, stream, q, ki, vi, o);
  } else {
    hipLaunchKernelGGL(fa_fwd_reg, dim3(512), dim3(512), 0, stream, q, k, v, o);
  }
}